// Round 1
// 660.757 us; speedup vs baseline: 1.0483x; 1.0483x over previous
//
#include <hip/hip_runtime.h>
#include <stdint.h>
#include <stddef.h>

#define D_HID 2304
#define NTOK  8192          // 4 * 2048
#define NQKV  6912          // 3 * 2304
#define WELEMS 5308416      // 2304*2304
#define SEQ_MASK 2047

typedef unsigned short u16;
typedef __bf16 bf16x8 __attribute__((ext_vector_type(8)));
typedef float  f32x16 __attribute__((ext_vector_type(16)));
typedef float  f32x4  __attribute__((ext_vector_type(4)));

__device__ __forceinline__ u16 f2bf(float f) {
    unsigned int u = __builtin_bit_cast(unsigned int, f);
    u += 0x7fffu + ((u >> 16) & 1u);           // RNE
    return (u16)(u >> 16);
}
__device__ __forceinline__ float bf2f(u16 h) {
    unsigned int u = ((unsigned int)h) << 16;
    return __builtin_bit_cast(float, u);
}

__device__ __forceinline__ void gl2lds16(const void* g, void* l) {
    __builtin_amdgcn_global_load_lds(
        (const __attribute__((address_space(1))) void*)g,
        (__attribute__((address_space(3))) void*)l,
        16, 0, 0);
}

// ---------------------------------------------------------------- converts
__global__ __launch_bounds__(256) void cvt_f32_bf16(
    const float* __restrict__ src, u16* __restrict__ dst)
{
    size_t i = ((size_t)blockIdx.x * 256 + threadIdx.x) * 4;
    float4 f = *(const float4*)(src + i);
    ushort4 o = make_ushort4(f2bf(f.x), f2bf(f.y), f2bf(f.z), f2bf(f.w));
    *(ushort4*)(dst + i) = o;
}

__global__ __launch_bounds__(256) void cvt_weights(
    const float* __restrict__ wq, const float* __restrict__ wk,
    const float* __restrict__ wv, const float* __restrict__ wo,
    u16* __restrict__ dst,
    const float* __restrict__ bq, const float* __restrict__ bk,
    const float* __restrict__ bv, float* __restrict__ bqkv)
{
    int i = blockIdx.x * 256 + threadIdx.x;
    if (i < NQKV)
        bqkv[i] = (i < 2304) ? bq[i] : (i < 4608) ? bk[i - 2304] : bv[i - 4608];
    size_t base = (size_t)i * 4;
    int r = (int)(base / WELEMS);
    const float* src = (r == 0) ? wq : (r == 1) ? wk : (r == 2) ? wv : wo;
    float4 f = *(const float4*)(src + (base - (size_t)r * WELEMS));
    ushort4 o = make_ushort4(f2bf(f.x), f2bf(f.y), f2bf(f.z), f2bf(f.w));
    *(ushort4*)(dst + base) = o;
}

// ---------------------------------------------------------------- GEMM 256^2 8-phase
// C[M,N] = A[M,K] * B[N,K]^T + bias, bf16 out. 512 thr = 8 waves (2M x 4N),
// per-wave 128x64 out via 16x16x32 MFMA (8x4 fragments, f32x4 each).
// LDS = 2 K-tile buffers x (A 256x64 + B 256x64) bf16 = 128 KiB.
// Schedule (per 64-K window, 4 phases): per-phase {ds_read subtile; stage one
// half-tile via global_load_lds; s_barrier; lgkmcnt(0); setprio(1); 16 MFMA;
// setprio(0); s_barrier}. Counted s_waitcnt vmcnt(6) ONLY at phase 4 keeps
// 3 half-tiles (6 loads) in flight across barriers (never drains to 0).
// Half-tile stage order for tile tau: B0,B1,A0 during window tau-2 (phases
// 2-4), A1 at window tau-1 phase 1 -> every half has >=4-phase issue->use lead,
// and vmcnt(6) at w4 proves tile t+1 landed before window t+1 starts.
// Slot-overwrite safety: B slots are only read in phase 1, A0 rows only read
// through phase 3 (all A reads front-loaded by phase 3); each phase's explicit
// lgkmcnt(0) + trailing barrier drains reads before the next phase's stage.
// LDS 16B-chunk slot c' of row r holds global chunk c = c' ^ (r&7): staging
// pre-swizzles the GLOBAL source (linear LDS dest, rule both-sides-or-neither),
// reads apply the same XOR -> 8 lanes per bank group on ds_read_b128 (optimal).
__global__ __launch_bounds__(512, 2) void gemm256_bt(
    const u16* __restrict__ A, const u16* __restrict__ B,
    const float* __restrict__ bias, u16* __restrict__ Cout,
    int M, int N, int K)
{
    __shared__ __align__(16) u16 lds2[65536];   // 128 KiB

    const int tid  = threadIdx.x;
    const int lane = tid & 63;
    const int wave = tid >> 6;
    const int NT   = K >> 6;                    // 64-k tiles (36 for K=2304)
    (void)M;

    // XCD-bijective swizzle (grid % 8 == 0), then bn-fast within each XCD's
    // chunk: each XCD owns 4 contiguous bm rows (2 A-panels L2-resident at a
    // time), B panels stream from L3.
    const int chunk = gridDim.x >> 3;
    const int bid = (blockIdx.x & 7) * chunk + (blockIdx.x >> 3);
    const int num_bn = N >> 8;
    const int bm = bid / num_bn;
    const int bn = bid - bm * num_bn;

    // ---- staging geometry: instr (wave, r) writes rows (r*8+wave)*8 .. +8
    // of a 128-row half; lane l -> row +(l>>3), LDS slot l&7; source chunk
    // pre-swizzled = (l&7) ^ (l>>3)  (row&7 == l>>3).
    const int srow = lane >> 3;
    const u16* __restrict__ Ast = A + (size_t)(bm * 256 + wave * 8 + srow) * K
                                    + ((lane & 7) ^ srow) * 8;
    const u16* __restrict__ Bst = B + (size_t)(bn * 256 + wave * 8 + srow) * K
                                    + ((lane & 7) ^ srow) * 8;
    const size_t row64  = (size_t)64 * K;
    const size_t row128 = (size_t)128 * K;
    const int ldsW = wave * 512;                // 1 KiB per (wave) within half

    // hsel: 0=A0 1=A1 2=B0 3=B1 of tile tt into buffer buf
#define STAGE(buf, hsel, tt) do {                                              \
    const u16* g_ = ((hsel) < 2 ? Ast : Bst)                                   \
                    + (((hsel) & 1) ? row128 : 0) + (size_t)(tt) * 64;         \
    u16* l_ = lds2 + (buf) * 32768 + (((hsel) < 2) ? 0 : 16384)                \
              + (((hsel) & 1) ? 8192 : 0) + ldsW;                              \
    gl2lds16(g_, l_);                                                          \
    gl2lds16(g_ + row64, l_ + 4096);                                           \
} while (0)

    // ---- read geometry (16x16x32 fragments): A row = m*16 + (l&15),
    // k-chunk = kk*4 + (l>>4); slot = chunk ^ (row&7), row&7 == lane&7.
    const int l15 = lane & 15, l4 = lane >> 4;
    const int aBase = (wave >> 2) * 8192 + l15 * 64;
    const int bBase = 16384 + ((wave >> 1) & 1) * 8192
                      + ((wave & 1) * 64 + l15) * 64;
    const int s0 = ((l4    ) ^ (lane & 7)) * 8;
    const int s1 = ((l4 + 4) ^ (lane & 7)) * 8;

    f32x4 acc[8][4] = {};

    // prologue: tile0 {B0,B1,A0,A1} + tile1 {B0,B1,A0}; drain tile0 only,
    // keep 3 half-tiles (6 loads) in flight.
    STAGE(0, 2, 0); STAGE(0, 3, 0); STAGE(0, 0, 0); STAGE(0, 1, 0);
    STAGE(1, 2, 1); STAGE(1, 3, 1); STAGE(1, 0, 1);
    asm volatile("s_waitcnt vmcnt(6)" ::: "memory");
    __builtin_amdgcn_s_barrier();

    for (int t = 0; t < NT; ++t) {
        const int cur = t & 1;
        const u16* lc = lds2 + cur * 32768;
        const bool stg2 = (t + 2 < NT);
        bf16x8 bfr[4][2], am[2][2], ah[4][2];

        // ---- phase 1: 12 ds_reads (all B + m0,m1); stage A1(t+1); MFMA m0,m1
#pragma unroll
        for (int n = 0; n < 4; ++n) {
            bfr[n][0] = *(const bf16x8*)(lc + bBase + n * 1024 + s0);
            bfr[n][1] = *(const bf16x8*)(lc + bBase + n * 1024 + s1);
        }
#pragma unroll
        for (int mo = 0; mo < 2; ++mo) {
            am[mo][0] = *(const bf16x8*)(lc + aBase + mo * 1024 + s0);
            am[mo][1] = *(const bf16x8*)(lc + aBase + mo * 1024 + s1);
        }
        if (t + 1 < NT) STAGE(cur ^ 1, 1, t + 1);
        __builtin_amdgcn_s_barrier();
        asm volatile("s_waitcnt lgkmcnt(0)" ::: "memory");
        __builtin_amdgcn_sched_barrier(0);
        __builtin_amdgcn_s_setprio(1);
#pragma unroll
        for (int kk = 0; kk < 2; ++kk)
#pragma unroll
            for (int mo = 0; mo < 2; ++mo)
#pragma unroll
                for (int n = 0; n < 4; ++n)
                    acc[mo][n] = __builtin_amdgcn_mfma_f32_16x16x32_bf16(
                        am[mo][kk], bfr[n][kk], acc[mo][n], 0, 0, 0);
        __builtin_amdgcn_s_setprio(0);
        __builtin_amdgcn_s_barrier();

        // ---- phase 2: 4 ds_reads (m2,m3); stage B0(t+2); MFMA m2,m3
#pragma unroll
        for (int mo = 0; mo < 2; ++mo) {
            am[mo][0] = *(const bf16x8*)(lc + aBase + (2 + mo) * 1024 + s0);
            am[mo][1] = *(const bf16x8*)(lc + aBase + (2 + mo) * 1024 + s1);
        }
        if (stg2) STAGE(cur, 2, t + 2);
        __builtin_amdgcn_s_barrier();
        asm volatile("s_waitcnt lgkmcnt(0)" ::: "memory");
        __builtin_amdgcn_sched_barrier(0);
        __builtin_amdgcn_s_setprio(1);
#pragma unroll
        for (int kk = 0; kk < 2; ++kk)
#pragma unroll
            for (int mo = 0; mo < 2; ++mo)
#pragma unroll
                for (int n = 0; n < 4; ++n)
                    acc[2 + mo][n] = __builtin_amdgcn_mfma_f32_16x16x32_bf16(
                        am[mo][kk], bfr[n][kk], acc[2 + mo][n], 0, 0, 0);
        __builtin_amdgcn_s_setprio(0);
        __builtin_amdgcn_s_barrier();

        // ---- phase 3: 8 ds_reads (m4..m7, front-loaded so A slots go quiet
        // before phase 4's A0 stage); stage B1(t+2); MFMA m4,m5
#pragma unroll
        for (int mo = 0; mo < 4; ++mo) {
            ah[mo][0] = *(const bf16x8*)(lc + aBase + (4 + mo) * 1024 + s0);
            ah[mo][1] = *(const bf16x8*)(lc + aBase + (4 + mo) * 1024 + s1);
        }
        if (stg2) STAGE(cur, 3, t + 2);
        __builtin_amdgcn_s_barrier();
        asm volatile("s_waitcnt lgkmcnt(0)" ::: "memory");
        __builtin_amdgcn_sched_barrier(0);
        __builtin_amdgcn_s_setprio(1);
#pragma unroll
        for (int kk = 0; kk < 2; ++kk)
#pragma unroll
            for (int mo = 0; mo < 2; ++mo)
#pragma unroll
                for (int n = 0; n < 4; ++n)
                    acc[4 + mo][n] = __builtin_amdgcn_mfma_f32_16x16x32_bf16(
                        ah[mo][kk], bfr[n][kk], acc[4 + mo][n], 0, 0, 0);
        __builtin_amdgcn_s_setprio(0);
        __builtin_amdgcn_s_barrier();

        // ---- phase 4: stage A0(t+2); MFMA m6,m7; counted vmcnt, never 0
        // in steady state (keeps 3 half-tiles of t+2 in flight).
        if (stg2) STAGE(cur, 0, t + 2);
        __builtin_amdgcn_s_barrier();
        __builtin_amdgcn_s_setprio(1);
#pragma unroll
        for (int kk = 0; kk < 2; ++kk)
#pragma unroll
            for (int mo = 0; mo < 2; ++mo)
#pragma unroll
                for (int n = 0; n < 4; ++n)
                    acc[6 + mo][n] = __builtin_amdgcn_mfma_f32_16x16x32_bf16(
                        ah[2 + mo][kk], bfr[n][kk], acc[6 + mo][n], 0, 0, 0);
        __builtin_amdgcn_s_setprio(0);
        if (t < NT - 2)       asm volatile("s_waitcnt vmcnt(6)" ::: "memory");
        else if (t == NT - 2) asm volatile("s_waitcnt vmcnt(0)" ::: "memory");
        __builtin_amdgcn_s_barrier();
    }
#undef STAGE

    // epilogue: C/D layout col = lane&15, row = (lane>>4)*4 + reg
    const int wm0 = (wave >> 2) * 128, wn0 = (wave & 3) * 64;
#pragma unroll
    for (int n = 0; n < 4; ++n) {
        const int gn = bn * 256 + wn0 + n * 16 + l15;
        const float bv = bias[gn];
#pragma unroll
        for (int m = 0; m < 8; ++m) {
            const int gm = bm * 256 + wm0 + m * 16 + l4 * 4;
#pragma unroll
            for (int j = 0; j < 4; ++j)
                Cout[(size_t)(gm + j) * N + gn] = f2bf(acc[m][n][j] + bv);
        }
    }
}

// ---------------------------------------------------------------- GEMM 128^2 (kept for O-proj)
// C[M,N] = A[M,K] * B[N,K]^T  (both K-major, bf16), fp32 accumulate.
// MODE 1: C = acc + bias + resid16 -> bf16 out (resid bf16)
template<int MODE>
__global__ __launch_bounds__(256, 3) void gemm_bt(
    const u16* __restrict__ A, const u16* __restrict__ B,
    const float* __restrict__ bias, u16* __restrict__ Cout,
    const u16* __restrict__ resid, int M, int N, int K)
{
    __shared__ __align__(16) u16 As[128 * 64];
    __shared__ __align__(16) u16 Bs[128 * 64];

    const int tid  = threadIdx.x;
    const int lane = tid & 63;
    const int wave = tid >> 6;

    // supertile decomposition: GROUP_M = 8 along bm, bm-fastest
    const int num_bn = N >> 7;
    const int rem = blockIdx.x % (num_bn << 3);
    const int bn  = rem >> 3;
    const int bm  = ((blockIdx.x / (num_bn << 3)) << 3) + (rem & 7);

    const int srow = tid >> 3;                        // 0..31
    const int sc   = (tid & 7) ^ (srow & 7);          // swizzle key = row&7
    const u16* Ag = A + (size_t)(bm * 128 + srow) * K + sc * 8;
    const u16* Bg = B + (size_t)(bn * 128 + srow) * K + sc * 8;
    const size_t row32 = (size_t)32 * K;
    u16* asd = As + wave * 512;                       // +r*2048 per round
    u16* bsd = Bs + wave * 512;

    const int rl = lane & 31;      // row within 32-tile (A: m, B: n)
    const int h  = lane >> 5;      // k-half of 16-k step
    const int swz = rl & 7;        // read-side swizzle key
    const int wm = (wave >> 1) * 64;
    const int wn = (wave & 1) * 64;

    f32x16 acc[2][2] = {};

    for (int kb = 0; kb < K; kb += 64) {
        __syncthreads();
#pragma unroll
        for (int r = 0; r < 4; ++r) {
            gl2lds16(Ag + kb + r * row32, asd + r * 2048);
            gl2lds16(Bg + kb + r * row32, bsd + r * 2048);
        }
        __syncthreads();

#pragma unroll
        for (int s = 0; s < 4; ++s) {                 // four 16-k steps
            const int ch = ((s * 2 + h) ^ swz) * 8;   // u16 offset of chunk
            bf16x8 a0 = *(const bf16x8*)(As + (wm      + rl) * 64 + ch);
            bf16x8 a1 = *(const bf16x8*)(As + (wm + 32 + rl) * 64 + ch);
            bf16x8 b0 = *(const bf16x8*)(Bs + (wn      + rl) * 64 + ch);
            bf16x8 b1 = *(const bf16x8*)(Bs + (wn + 32 + rl) * 64 + ch);
            acc[0][0] = __builtin_amdgcn_mfma_f32_32x32x16_bf16(a0, b0, acc[0][0], 0, 0, 0);
            acc[0][1] = __builtin_amdgcn_mfma_f32_32x32x16_bf16(a0, b1, acc[0][1], 0, 0, 0);
            acc[1][0] = __builtin_amdgcn_mfma_f32_32x32x16_bf16(a1, b0, acc[1][0], 0, 0, 0);
            acc[1][1] = __builtin_amdgcn_mfma_f32_32x32x16_bf16(a1, b1, acc[1][1], 0, 0, 0);
        }
    }

    // epilogue: C/D layout col = lane&31, row = (reg&3) + 8*(reg>>2) + 4*h
#pragma unroll
    for (int mt = 0; mt < 2; ++mt) {
#pragma unroll
        for (int nt = 0; nt < 2; ++nt) {
            const int gn = bn * 128 + wn + nt * 32 + rl;
            const float bv = bias[gn];
#pragma unroll
            for (int reg = 0; reg < 16; ++reg) {
                const int gm = bm * 128 + wm + mt * 32 +
                               (reg & 3) + 8 * (reg >> 2) + 4 * h;
                const size_t idx = (size_t)gm * N + gn;
                float v = acc[mt][nt][reg] + bv;
                if constexpr (MODE == 1) v += bf2f(resid[idx]);
                Cout[idx] = f2bf(v);
            }
        }
    }
}

// ---------------------------------------------------------------- attention
// One block per token. q/k/v staged as [16 heads][148 floats] (pad 144->148:
// row-to-row bank offset = 20 -> strided head reads conflict-free).
// S = QK^T/12 over d=144 per head pair, softmax over m (stored transposed),
// O-step: 144 tasks of (4 cols x 4 heads) with float4 W and V reads.
#define HROW 148
__global__ __launch_bounds__(256) void attn_headmix(
    const u16* __restrict__ QKV, u16* __restrict__ Aout)
{
    __shared__ __align__(16) float qs[16 * HROW];
    __shared__ __align__(16) float ks[16 * HROW];
    __shared__ __align__(16) float vs[16 * HROW];
    __shared__ __align__(16) float wsmT[256];   // wsmT[m][n]

    const int tid = threadIdx.x;
    const int t   = blockIdx.x;
    const float fpos = (float)(t & SEQ_MASK);
    const u16* row = QKV + (size_t)t * NQKV;

    const float OMEGA_C = -2.0f * 13.287712379549449f / 2304.0f; // -2*log2(1e4)/d
    const float INV2PI  = 0.15915494309189535f;

    for (int c = tid; c < 864; c += 256) {       // 864 chunks of 8 bf16
        uint4 raw = *(const uint4*)(row + c * 8);
        float f[8];
        f[0] = bf2f(raw.x & 0xffff); f[1] = bf2f(raw.x >> 16);
        f[2] = bf2f(raw.y & 0xffff); f[3] = bf2f(raw.y >> 16);
        f[4] = bf2f(raw.z & 0xffff); f[5] = bf2f(raw.z >> 16);
        f[6] = bf2f(raw.w & 0xffff); f[7] = bf2f(raw.w >> 16);
        if (c < 576) {                            // q or k chunk -> RoPE
            const int cc = (c < 288) ? c : c - 288;
            const int p0 = cc * 4;                // pair index in full 2304
#pragma unroll
            for (int jp = 0; jp < 4; ++jp) {
                float omega = exp2f((float)(p0 + jp) * OMEGA_C);
                float rr = fpos * omega * INV2PI;
                rr -= floorf(rr);
                float sn = __builtin_amdgcn_sinf(rr);
                float cs = __builtin_amdgcn_cosf(rr);
                float x0 = f[2 * jp], x1 = f[2 * jp + 1];
                f[2 * jp]     = cs * x0 - sn * x1;
                f[2 * jp + 1] = sn * x0 + cs * x1;
            }
            const int hr = cc / 18, col = (cc - hr * 18) * 8;  // 18 chunks/head
            float* dst = ((c < 288) ? qs : ks) + hr * HROW + col;
            *(float4*)(dst)     = make_float4(f[0], f[1], f[2], f[3]);
            *(float4*)(dst + 4) = make_float4(f[4], f[5], f[6], f[7]);
        } else {
            const int cv = c - 576;
            const int hr = cv / 18, col = (cv - hr * 18) * 8;
            float* dst = vs + hr * HROW + col;
            *(float4*)(dst)     = make_float4(f[0], f[1], f[2], f[3]);
            *(float4*)(dst + 4) = make_float4(f[4], f[5], f[6], f[7]);
        }
    }
    __syncthreads();

    // S[n][m]: thread (n = tid>>4, m = tid&15)
    const int n = tid >> 4, m = tid & 15;
    const float* qr = qs + n * HROW;
    const float* kr = ks + m * HROW;
    float s = 0.f;
#pragma unroll
    for (int d = 0; d < 144; d += 4) {
        float4 qv = *(const float4*)(qr + d);
        float4 kv = *(const float4*)(kr + d);
        s += qv.x * kv.x + qv.y * kv.y + qv.z * kv.z + qv.w * kv.w;
    }
    s *= (1.0f / 12.0f);                         // 1/sqrt(144)

    float mx = s;
#pragma unroll
    for (int off = 8; off >= 1; off >>= 1) mx = fmaxf(mx, __shfl_xor(mx, off));
    float e = __expf(s - mx);
    float sum = e;
#pragma unroll
    for (int off = 8; off >= 1; off >>= 1) sum += __shfl_xor(sum, off);
    wsmT[m * 16 + n] = e / sum;                  // transposed store
    __syncthreads();

    // O: task = (col4 = 0..35, nq = 0..3); 144 active threads
    if (tid < 144) {
        const int col4 = tid % 36;
        const int nq   = tid / 36;
        const int oc   = col4 * 4;
        float4 a0 = {0,0,0,0}, a1 = {0,0,0,0}, a2 = {0,0,0,0}, a3 = {0,0,0,0};
#pragma unroll
        for (int mm = 0; mm < 16; ++mm) {
            float4 w4 = *(const float4*)(wsmT + mm * 16 + nq * 4);
            float4 v4 = *(const float4*)(vs + mm * HROW + oc);
            a0.x += w4.x * v4.x; a0.y += w4.x * v4.y; a0.z += w4.x * v4.z; a0.w += w4.x * v4.w;
            a1.x += w4.y * v4.x; a1.y += w4.y * v4.y; a1.z += w4.y * v4.z; a1.w += w4.y * v4.w;
            a2.x += w4.z * v4.x; a2.y += w4.z * v4.y; a2.z += w4.z * v4.z; a2.w += w4.z * v4.w;
            a3.x += w4.w * v4.x; a3.y += w4.w * v4.y; a3.z += w4.w * v4.z; a3.w += w4.w * v4.w;
        }
        u16* orow = Aout + (size_t)t * D_HID;
        float4 accs[4] = {a0, a1, a2, a3};
#pragma unroll
        for (int i = 0; i < 4; ++i) {
            const int nn = nq * 4 + i;
            ushort4 o = make_ushort4(f2bf(accs[i].x), f2bf(accs[i].y),
                                     f2bf(accs[i].z), f2bf(accs[i].w));
            *(ushort4*)(orow + nn * 144 + oc) = o;
        }
    }
}

// ---------------------------------------------------------------- layernorm
__global__ __launch_bounds__(256) void ln_kernel(
    const u16* __restrict__ Y, const float* __restrict__ g,
    const float* __restrict__ b, float* __restrict__ out)
{
    const int tid  = threadIdx.x;
    const u16* y = Y + (size_t)blockIdx.x * D_HID;
    float v[9];
    float s = 0.f, s2 = 0.f;
#pragma unroll
    for (int r = 0; r < 9; ++r) {
        v[r] = bf2f(y[tid + r * 256]);
        s += v[r]; s2 += v[r] * v[r];
    }
#pragma unroll
    for (int off = 32; off >= 1; off >>= 1) {
        s  += __shfl_xor(s, off);
        s2 += __shfl_xor(s2, off);
    }
    __shared__ float red[8];
    const int wave = tid >> 6;
    if ((tid & 63) == 0) { red[wave] = s; red[4 + wave] = s2; }
    __syncthreads();
    s  = red[0] + red[1] + red[2] + red[3];
    s2 = red[4] + red[5] + red[6] + red[7];
    const float inv_n = 1.0f / 2304.0f;
    float mu  = s * inv_n;
    float var = fmaxf(s2 * inv_n - mu * mu, 0.f);
    float inv = rsqrtf(var + 1e-5f);
    float* orow = out + (size_t)blockIdx.x * D_HID;
#pragma unroll
    for (int r = 0; r < 9; ++r) {
        int c = tid + r * 256;
        orow[c] = (v[r] - mu) * inv * g[c] + b[c];
    }
}

// ---------------------------------------------------------------- launch
extern "C" void kernel_launch(void* const* d_in, const int* in_sizes, int n_in,
                              void* d_out, int out_size, void* d_ws, size_t ws_size,
                              hipStream_t stream)
{
    const float* x   = (const float*)d_in[0];
    const float* wq  = (const float*)d_in[1];
    const float* bq  = (const float*)d_in[2];
    const float* wk  = (const float*)d_in[3];
    const float* bk  = (const float*)d_in[4];
    const float* wv  = (const float*)d_in[5];
    const float* bv  = (const float*)d_in[6];
    const float* wo  = (const float*)d_in[7];
    const float* bo  = (const float*)d_in[8];
    const float* lng = (const float*)d_in[9];
    const float* lnb = (const float*)d_in[10];

    char* ws = (char*)d_ws;
    size_t off = 0;
    auto alloc = [&](size_t bytes) {
        void* p = ws + off;
        off += (bytes + 255) & ~(size_t)255;
        return p;
    };
    u16*   xb   = (u16*)alloc((size_t)NTOK * D_HID * 2);
    u16*   wqkv = (u16*)alloc((size_t)(NQKV + D_HID) * D_HID * 2);
    u16*   wob  = wqkv + (size_t)NQKV * D_HID;
    float* bqkv = (float*)alloc((size_t)NQKV * 4);
    u16*   qkv  = (u16*)alloc((size_t)NTOK * NQKV * 2);
    u16*   aout = (u16*)alloc((size_t)NTOK * D_HID * 2);
    u16*   ybuf = qkv;  // QKV dead after attention; reuse for bf16 y

    cvt_f32_bf16<<<NTOK * D_HID / 1024, 256, 0, stream>>>(x, xb);
    cvt_weights<<<4 * WELEMS / 1024, 256, 0, stream>>>(wq, wk, wv, wo, wqkv,
                                                       bq, bk, bv, bqkv);
    gemm256_bt<<<(NTOK / 256) * (NQKV / 256), 512, 0, stream>>>(
        xb, wqkv, bqkv, qkv, NTOK, NQKV, D_HID);
    attn_headmix<<<NTOK, 256, 0, stream>>>(qkv, aout);
    gemm_bt<1><<<(D_HID / 128) * (NTOK / 128), 256, 0, stream>>>(
        aout, wob, bo, ybuf, xb, NTOK, D_HID, D_HID);
    ln_kernel<<<NTOK, 256, 0, stream>>>(ybuf, lng, lnb, (float*)d_out);
}

// Round 3
// 654.908 us; speedup vs baseline: 1.0577x; 1.0089x over previous
//
#include <hip/hip_runtime.h>
#include <stdint.h>
#include <stddef.h>

#define D_HID 2304
#define NTOK  8192          // 4 * 2048
#define NQKV  6912          // 3 * 2304
#define WELEMS 5308416      // 2304*2304
#define SEQ_MASK 2047

typedef unsigned short u16;
typedef __bf16 bf16x8 __attribute__((ext_vector_type(8)));
typedef float  f32x16 __attribute__((ext_vector_type(16)));
typedef float  f32x4  __attribute__((ext_vector_type(4)));

__device__ __forceinline__ u16 f2bf(float f) {
    unsigned int u = __builtin_bit_cast(unsigned int, f);
    u += 0x7fffu + ((u >> 16) & 1u);           // RNE
    return (u16)(u >> 16);
}
__device__ __forceinline__ float bf2f(u16 h) {
    unsigned int u = ((unsigned int)h) << 16;
    return __builtin_bit_cast(float, u);
}

__device__ __forceinline__ void gl2lds16(const void* g, void* l) {
    __builtin_amdgcn_global_load_lds(
        (const __attribute__((address_space(1))) void*)g,
        (__attribute__((address_space(3))) void*)l,
        16, 0, 0);
}

// ---------------------------------------------------------------- converts
__global__ __launch_bounds__(256) void cvt_f32_bf16(
    const float* __restrict__ src, u16* __restrict__ dst)
{
    size_t i = ((size_t)blockIdx.x * 256 + threadIdx.x) * 4;
    float4 f = *(const float4*)(src + i);
    ushort4 o = make_ushort4(f2bf(f.x), f2bf(f.y), f2bf(f.z), f2bf(f.w));
    *(ushort4*)(dst + i) = o;
}

__global__ __launch_bounds__(256) void cvt_weights(
    const float* __restrict__ wq, const float* __restrict__ wk,
    const float* __restrict__ wv, const float* __restrict__ wo,
    u16* __restrict__ dst,
    const float* __restrict__ bq, const float* __restrict__ bk,
    const float* __restrict__ bv, float* __restrict__ bqkv)
{
    int i = blockIdx.x * 256 + threadIdx.x;
    if (i < NQKV)
        bqkv[i] = (i < 2304) ? bq[i] : (i < 4608) ? bk[i - 2304] : bv[i - 4608];
    size_t base = (size_t)i * 4;
    int r = (int)(base / WELEMS);
    const float* src = (r == 0) ? wq : (r == 1) ? wk : (r == 2) ? wv : wo;
    float4 f = *(const float4*)(src + (base - (size_t)r * WELEMS));
    ushort4 o = make_ushort4(f2bf(f.x), f2bf(f.y), f2bf(f.z), f2bf(f.w));
    *(ushort4*)(dst + base) = o;
}

// ---------------------------------------------------------------- GEMM 256^2, read-pipelined 4-phase
// C[M,N] = A[M,K] * B[N,K]^T + bias, bf16 out. 512 thr = 8 waves (2M x 4N),
// per-wave 128x64 out via 16x16x32 MFMA. LDS = 2 K-tile buffers = 128 KiB.
//
// Phases are split by k-half (kk0 phases 1-2, kk1 phases 3-4); each phase's
// fragment ds_reads are issued ONE PHASE AHEAD of their MFMA, so the LDS
// drain hides under the previous MFMA cluster (compiler emits counted
// lgkmcnt before first use; never a drain-before-MFMA).
//   ph1: rd {Bk1(t), Aq1}        stage A1(t+1)->c^1   MFMA m0-3 x kk0
//   ph2: rd {Aq2}                stage B0(t+2)->c     MFMA m4-7 x kk0  lgkm0
//   ph3: rd {Aq3}  stage B1(t+2)->c  vmcnt(4) midbar  rd {Bk0(t+1)<-c^1}
//                                                     MFMA m0-3 x kk1  lgkm0
//   ph4: stage A0(t+2)->c  rd {Aq0(t+1)<-c^1}         MFMA m4-7 x kk1  lgkm0
// Race discipline: every LDS slot's reads are drained (post-MFMA lgkm0 +
// trailing barrier) before the STAGE that overwrites that slot issues:
//   Bk1(t) reads [ph1] drained ph2-lgkm0  < stage B1(t+2) [ph3]
//   Aq1..Aq3 reads drained by ph2/ph3 lgkm0 < stage A0(t+2) [ph4]
//   Bk0(t+1)/Aq0(t+1) reads from c^1 drained ph3/ph4 lgkm0 < t+1-ph1 stages
// vmcnt(4) at ph3 retires A1(t+1) (in-order => ALL of tile t+1 landed);
// mid-barrier makes that cross-wave before the c^1 pre-reads. Counted vmcnt
// never drains to 0 in steady state (B0/B1(t+2) stay in flight).
// LDS 16B-chunk slot c' of row r holds global chunk c = c' ^ (r&7)
// (pre-swizzled global source, linear LDS dest, swizzled read).
__global__ __launch_bounds__(512, 2) void gemm256_bt(
    const u16* __restrict__ A, const u16* __restrict__ B,
    const float* __restrict__ bias, u16* __restrict__ Cout,
    int M, int N, int K)
{
    __shared__ __align__(16) u16 lds2[65536];   // 128 KiB

    const int tid  = threadIdx.x;
    const int lane = tid & 63;
    const int wave = tid >> 6;
    const int NT   = K >> 6;                    // 64-k tiles (36 for K=2304)
    (void)M;

    // XCD-bijective swizzle (grid % 8 == 0), bn-fast within each XCD chunk.
    const int chunk = gridDim.x >> 3;
    const int bid = (blockIdx.x & 7) * chunk + (blockIdx.x >> 3);
    const int num_bn = N >> 8;
    const int bm = bid / num_bn;
    const int bn = bid - bm * num_bn;

    // staging geometry: instr (wave, half) writes rows wave*8..+8 of a
    // 64-row stripe; lane l -> row +(l>>3), LDS slot l&7, source chunk
    // pre-swizzled = (l&7) ^ (l>>3).
    const int srow = lane >> 3;
    const u16* __restrict__ Ast = A + (size_t)(bm * 256 + wave * 8 + srow) * K
                                    + ((lane & 7) ^ srow) * 8;
    const u16* __restrict__ Bst = B + (size_t)(bn * 256 + wave * 8 + srow) * K
                                    + ((lane & 7) ^ srow) * 8;
    const size_t row64  = (size_t)64 * K;
    const size_t row128 = (size_t)128 * K;
    const int ldsW = wave * 512;

    // hsel: 0=A0 1=A1 2=B0 3=B1 of tile tt into buffer buf
#define STAGE(buf, hsel, tt) do {                                              \
    const u16* g_ = ((hsel) < 2 ? Ast : Bst)                                   \
                    + (((hsel) & 1) ? row128 : 0) + (size_t)(tt) * 64;         \
    u16* l_ = lds2 + (buf) * 32768 + (((hsel) < 2) ? 0 : 16384)                \
              + (((hsel) & 1) ? 8192 : 0) + ldsW;                              \
    gl2lds16(g_, l_);                                                          \
    gl2lds16(g_ + row64, l_ + 4096);                                           \
} while (0)

    // read geometry (16x16x32 fragments): row = mo*16 + (l&15),
    // k-chunk slot = (kk*4 + l>>4) ^ (lane&7).
    const int l15 = lane & 15, l4 = lane >> 4;
    const int aBase = (wave >> 2) * 8192 + l15 * 64;
    const int bBase = 16384 + ((wave >> 1) & 1) * 8192
                      + ((wave & 1) * 64 + l15) * 64;
    const int s0 = ((l4    ) ^ (lane & 7)) * 8;
    const int s1 = ((l4 + 4) ^ (lane & 7)) * 8;

    f32x4 acc[8][4] = {};
    bf16x8 Bk0[4], Bk1[4], Aev[4], Aod[4];

    // prologue: tile0 {B0,B1,A0,A1} + tile1 {B0,B1,A0}; vmcnt(6) retires
    // exactly tile0's 8 loads; preload tile0's kk0 fragments.
    STAGE(0, 2, 0); STAGE(0, 3, 0); STAGE(0, 0, 0); STAGE(0, 1, 0);
    STAGE(1, 2, 1); STAGE(1, 3, 1); STAGE(1, 0, 1);
    asm volatile("s_waitcnt vmcnt(6)" ::: "memory");
    __builtin_amdgcn_s_barrier();
#pragma unroll
    for (int n = 0; n < 4; ++n)
        Bk0[n] = *(const bf16x8*)(lds2 + bBase + n * 1024 + s0);
#pragma unroll
    for (int mo = 0; mo < 4; ++mo)
        Aev[mo] = *(const bf16x8*)(lds2 + aBase + mo * 1024 + s0);

    for (int t = 0; t < NT; ++t) {
        const int cur = t & 1;
        const u16* lc = lds2 + cur * 32768;
        const u16* ln = lds2 + (cur ^ 1) * 32768;
        const bool st1 = (t + 1 < NT);
        const bool st2 = (t + 2 < NT);

        // ---- phase 1: rd Bk1(t)+Aq1; stage A1(t+1); MFMA m0-3 kk0
#pragma unroll
        for (int n = 0; n < 4; ++n)
            Bk1[n] = *(const bf16x8*)(lc + bBase + n * 1024 + s1);
#pragma unroll
        for (int mo = 0; mo < 4; ++mo)
            Aod[mo] = *(const bf16x8*)(lc + aBase + (4 + mo) * 1024 + s0);
        if (st1) STAGE(cur ^ 1, 1, t + 1);
        __builtin_amdgcn_sched_barrier(0);
        __builtin_amdgcn_s_setprio(1);
#pragma unroll
        for (int mo = 0; mo < 4; ++mo)
#pragma unroll
            for (int n = 0; n < 4; ++n)
                acc[mo][n] = __builtin_amdgcn_mfma_f32_16x16x32_bf16(
                    Aev[mo], Bk0[n], acc[mo][n], 0, 0, 0);
        __builtin_amdgcn_s_setprio(0);
        __builtin_amdgcn_sched_barrier(0);
        __builtin_amdgcn_s_barrier();

        // ---- phase 2: rd Aq2; stage B0(t+2); MFMA m4-7 kk0; lgkm0
#pragma unroll
        for (int mo = 0; mo < 4; ++mo)
            Aev[mo] = *(const bf16x8*)(lc + aBase + mo * 1024 + s1);
        if (st2) STAGE(cur, 2, t + 2);
        __builtin_amdgcn_sched_barrier(0);
        __builtin_amdgcn_s_setprio(1);
#pragma unroll
        for (int mo = 0; mo < 4; ++mo)
#pragma unroll
            for (int n = 0; n < 4; ++n)
                acc[4 + mo][n] = __builtin_amdgcn_mfma_f32_16x16x32_bf16(
                    Aod[mo], Bk0[n], acc[4 + mo][n], 0, 0, 0);
        __builtin_amdgcn_s_setprio(0);
        __builtin_amdgcn_sched_barrier(0);
        asm volatile("s_waitcnt lgkmcnt(0)" ::: "memory");
        __builtin_amdgcn_s_barrier();

        // ---- phase 3: rd Aq3; stage B1(t+2); vmcnt + mid-barrier;
        //      rd Bk0(t+1) from c^1; MFMA m0-3 kk1; lgkm0
#pragma unroll
        for (int mo = 0; mo < 4; ++mo)
            Aod[mo] = *(const bf16x8*)(lc + aBase + (4 + mo) * 1024 + s1);
        if (st2) STAGE(cur, 3, t + 2);
        if (st2)      asm volatile("s_waitcnt vmcnt(4)" ::: "memory");
        else if (st1) asm volatile("s_waitcnt vmcnt(0)" ::: "memory");
        if (st1) {
            __builtin_amdgcn_s_barrier();      // c^1 now visible to all waves
#pragma unroll
            for (int n = 0; n < 4; ++n)
                Bk0[n] = *(const bf16x8*)(ln + bBase + n * 1024 + s0);
        }
        __builtin_amdgcn_sched_barrier(0);
        __builtin_amdgcn_s_setprio(1);
#pragma unroll
        for (int mo = 0; mo < 4; ++mo)
#pragma unroll
            for (int n = 0; n < 4; ++n)
                acc[mo][n] = __builtin_amdgcn_mfma_f32_16x16x32_bf16(
                    Aev[mo], Bk1[n], acc[mo][n], 0, 0, 0);
        __builtin_amdgcn_s_setprio(0);
        __builtin_amdgcn_sched_barrier(0);
        asm volatile("s_waitcnt lgkmcnt(0)" ::: "memory");
        __builtin_amdgcn_s_barrier();

        // ---- phase 4: stage A0(t+2); rd Aq0(t+1) from c^1; MFMA m4-7 kk1
        if (st2) STAGE(cur, 0, t + 2);
        if (st1) {
#pragma unroll
            for (int mo = 0; mo < 4; ++mo)
                Aev[mo] = *(const bf16x8*)(ln + aBase + mo * 1024 + s0);
        }
        __builtin_amdgcn_sched_barrier(0);
        __builtin_amdgcn_s_setprio(1);
#pragma unroll
        for (int mo = 0; mo < 4; ++mo)
#pragma unroll
            for (int n = 0; n < 4; ++n)
                acc[4 + mo][n] = __builtin_amdgcn_mfma_f32_16x16x32_bf16(
                    Aod[mo], Bk1[n], acc[4 + mo][n], 0, 0, 0);
        __builtin_amdgcn_s_setprio(0);
        __builtin_amdgcn_sched_barrier(0);
        asm volatile("s_waitcnt lgkmcnt(0)" ::: "memory");
        __builtin_amdgcn_s_barrier();
    }
#undef STAGE

    // epilogue: C/D layout col = lane&15, row = (lane>>4)*4 + reg
    const int wm0 = (wave >> 2) * 128, wn0 = (wave & 3) * 64;
#pragma unroll
    for (int n = 0; n < 4; ++n) {
        const int gn = bn * 256 + wn0 + n * 16 + l15;
        const float bv = bias[gn];
#pragma unroll
        for (int m = 0; m < 8; ++m) {
            const int gm = bm * 256 + wm0 + m * 16 + l4 * 4;
#pragma unroll
            for (int j = 0; j < 4; ++j)
                Cout[(size_t)(gm + j) * N + gn] = f2bf(acc[m][n][j] + bv);
        }
    }
}

// ---------------------------------------------------------------- GEMM 128^2 (kept for O-proj)
// C[M,N] = A[M,K] * B[N,K]^T  (both K-major, bf16), fp32 accumulate.
// MODE 1: C = acc + bias + resid16 -> bf16 out (resid bf16)
template<int MODE>
__global__ __launch_bounds__(256, 3) void gemm_bt(
    const u16* __restrict__ A, const u16* __restrict__ B,
    const float* __restrict__ bias, u16* __restrict__ Cout,
    const u16* __restrict__ resid, int M, int N, int K)
{
    __shared__ __align__(16) u16 As[128 * 64];
    __shared__ __align__(16) u16 Bs[128 * 64];

    const int tid  = threadIdx.x;
    const int lane = tid & 63;
    const int wave = tid >> 6;

    // supertile decomposition: GROUP_M = 8 along bm, bm-fastest
    const int num_bn = N >> 7;
    const int rem = blockIdx.x % (num_bn << 3);
    const int bn  = rem >> 3;
    const int bm  = ((blockIdx.x / (num_bn << 3)) << 3) + (rem & 7);

    const int srow = tid >> 3;                        // 0..31
    const int sc   = (tid & 7) ^ (srow & 7);          // swizzle key = row&7
    const u16* Ag = A + (size_t)(bm * 128 + srow) * K + sc * 8;
    const u16* Bg = B + (size_t)(bn * 128 + srow) * K + sc * 8;
    const size_t row32 = (size_t)32 * K;
    u16* asd = As + wave * 512;                       // +r*2048 per round
    u16* bsd = Bs + wave * 512;

    const int rl = lane & 31;      // row within 32-tile (A: m, B: n)
    const int h  = lane >> 5;      // k-half of 16-k step
    const int swz = rl & 7;        // read-side swizzle key
    const int wm = (wave >> 1) * 64;
    const int wn = (wave & 1) * 64;

    f32x16 acc[2][2] = {};

    for (int kb = 0; kb < K; kb += 64) {
        __syncthreads();
#pragma unroll
        for (int r = 0; r < 4; ++r) {
            gl2lds16(Ag + kb + r * row32, asd + r * 2048);
            gl2lds16(Bg + kb + r * row32, bsd + r * 2048);
        }
        __syncthreads();

#pragma unroll
        for (int s = 0; s < 4; ++s) {                 // four 16-k steps
            const int ch = ((s * 2 + h) ^ swz) * 8;   // u16 offset of chunk
            bf16x8 a0 = *(const bf16x8*)(As + (wm      + rl) * 64 + ch);
            bf16x8 a1 = *(const bf16x8*)(As + (wm + 32 + rl) * 64 + ch);
            bf16x8 b0 = *(const bf16x8*)(Bs + (wn      + rl) * 64 + ch);
            bf16x8 b1 = *(const bf16x8*)(Bs + (wn + 32 + rl) * 64 + ch);
            acc[0][0] = __builtin_amdgcn_mfma_f32_32x32x16_bf16(a0, b0, acc[0][0], 0, 0, 0);
            acc[0][1] = __builtin_amdgcn_mfma_f32_32x32x16_bf16(a0, b1, acc[0][1], 0, 0, 0);
            acc[1][0] = __builtin_amdgcn_mfma_f32_32x32x16_bf16(a1, b0, acc[1][0], 0, 0, 0);
            acc[1][1] = __builtin_amdgcn_mfma_f32_32x32x16_bf16(a1, b1, acc[1][1], 0, 0, 0);
        }
    }

    // epilogue: C/D layout col = lane&31, row = (reg&3) + 8*(reg>>2) + 4*h
#pragma unroll
    for (int mt = 0; mt < 2; ++mt) {
#pragma unroll
        for (int nt = 0; nt < 2; ++nt) {
            const int gn = bn * 128 + wn + nt * 32 + rl;
            const float bv = bias[gn];
#pragma unroll
            for (int reg = 0; reg < 16; ++reg) {
                const int gm = bm * 128 + wm + mt * 32 +
                               (reg & 3) + 8 * (reg >> 2) + 4 * h;
                const size_t idx = (size_t)gm * N + gn;
                float v = acc[mt][nt][reg] + bv;
                if constexpr (MODE == 1) v += bf2f(resid[idx]);
                Cout[idx] = f2bf(v);
            }
        }
    }
}

// ---------------------------------------------------------------- attention
// One block per token. q/k/v staged as [16 heads][148 floats] (pad 144->148:
// row-to-row bank offset = 20 -> strided head reads conflict-free).
// S = QK^T/12 over d=144 per head pair, softmax over m (stored transposed),
// O-step: 144 tasks of (4 cols x 4 heads) with float4 W and V reads.
#define HROW 148
__global__ __launch_bounds__(256) void attn_headmix(
    const u16* __restrict__ QKV, u16* __restrict__ Aout)
{
    __shared__ __align__(16) float qs[16 * HROW];
    __shared__ __align__(16) float ks[16 * HROW];
    __shared__ __align__(16) float vs[16 * HROW];
    __shared__ __align__(16) float wsmT[256];   // wsmT[m][n]

    const int tid = threadIdx.x;
    const int t   = blockIdx.x;
    const float fpos = (float)(t & SEQ_MASK);
    const u16* row = QKV + (size_t)t * NQKV;

    const float OMEGA_C = -2.0f * 13.287712379549449f / 2304.0f; // -2*log2(1e4)/d
    const float INV2PI  = 0.15915494309189535f;

    for (int c = tid; c < 864; c += 256) {       // 864 chunks of 8 bf16
        uint4 raw = *(const uint4*)(row + c * 8);
        float f[8];
        f[0] = bf2f(raw.x & 0xffff); f[1] = bf2f(raw.x >> 16);
        f[2] = bf2f(raw.y & 0xffff); f[3] = bf2f(raw.y >> 16);
        f[4] = bf2f(raw.z & 0xffff); f[5] = bf2f(raw.z >> 16);
        f[6] = bf2f(raw.w & 0xffff); f[7] = bf2f(raw.w >> 16);
        if (c < 576) {                            // q or k chunk -> RoPE
            const int cc = (c < 288) ? c : c - 288;
            const int p0 = cc * 4;                // pair index in full 2304
#pragma unroll
            for (int jp = 0; jp < 4; ++jp) {
                float omega = exp2f((float)(p0 + jp) * OMEGA_C);
                float rr = fpos * omega * INV2PI;
                rr -= floorf(rr);
                float sn = __builtin_amdgcn_sinf(rr);
                float cs = __builtin_amdgcn_cosf(rr);
                float x0 = f[2 * jp], x1 = f[2 * jp + 1];
                f[2 * jp]     = cs * x0 - sn * x1;
                f[2 * jp + 1] = sn * x0 + cs * x1;
            }
            const int hr = cc / 18, col = (cc - hr * 18) * 8;  // 18 chunks/head
            float* dst = ((c < 288) ? qs : ks) + hr * HROW + col;
            *(float4*)(dst)     = make_float4(f[0], f[1], f[2], f[3]);
            *(float4*)(dst + 4) = make_float4(f[4], f[5], f[6], f[7]);
        } else {
            const int cv = c - 576;
            const int hr = cv / 18, col = (cv - hr * 18) * 8;
            float* dst = vs + hr * HROW + col;
            *(float4*)(dst)     = make_float4(f[0], f[1], f[2], f[3]);
            *(float4*)(dst + 4) = make_float4(f[4], f[5], f[6], f[7]);
        }
    }
    __syncthreads();

    // S[n][m]: thread (n = tid>>4, m = tid&15)
    const int n = tid >> 4, m = tid & 15;
    const float* qr = qs + n * HROW;
    const float* kr = ks + m * HROW;
    float s = 0.f;
#pragma unroll
    for (int d = 0; d < 144; d += 4) {
        float4 qv = *(const float4*)(qr + d);
        float4 kv = *(const float4*)(kr + d);
        s += qv.x * kv.x + qv.y * kv.y + qv.z * kv.z + qv.w * kv.w;
    }
    s *= (1.0f / 12.0f);                         // 1/sqrt(144)

    float mx = s;
#pragma unroll
    for (int off = 8; off >= 1; off >>= 1) mx = fmaxf(mx, __shfl_xor(mx, off));
    float e = __expf(s - mx);
    float sum = e;
#pragma unroll
    for (int off = 8; off >= 1; off >>= 1) sum += __shfl_xor(sum, off);
    wsmT[m * 16 + n] = e / sum;                  // transposed store
    __syncthreads();

    // O: task = (col4 = 0..35, nq = 0..3); 144 active threads
    if (tid < 144) {
        const int col4 = tid % 36;
        const int nq   = tid / 36;
        const int oc   = col4 * 4;
        float4 a0 = {0,0,0,0}, a1 = {0,0,0,0}, a2 = {0,0,0,0}, a3 = {0,0,0,0};
#pragma unroll
        for (int mm = 0; mm < 16; ++mm) {
            float4 w4 = *(const float4*)(wsmT + mm * 16 + nq * 4);
            float4 v4 = *(const float4*)(vs + mm * HROW + oc);
            a0.x += w4.x * v4.x; a0.y += w4.x * v4.y; a0.z += w4.x * v4.z; a0.w += w4.x * v4.w;
            a1.x += w4.y * v4.x; a1.y += w4.y * v4.y; a1.z += w4.y * v4.z; a1.w += w4.y * v4.w;
            a2.x += w4.z * v4.x; a2.y += w4.z * v4.y; a2.z += w4.z * v4.z; a2.w += w4.z * v4.w;
            a3.x += w4.w * v4.x; a3.y += w4.w * v4.y; a3.z += w4.w * v4.z; a3.w += w4.w * v4.w;
        }
        u16* orow = Aout + (size_t)t * D_HID;
        float4 accs[4] = {a0, a1, a2, a3};
#pragma unroll
        for (int i = 0; i < 4; ++i) {
            const int nn = nq * 4 + i;
            ushort4 o = make_ushort4(f2bf(accs[i].x), f2bf(accs[i].y),
                                     f2bf(accs[i].z), f2bf(accs[i].w));
            *(ushort4*)(orow + nn * 144 + oc) = o;
        }
    }
}

// ---------------------------------------------------------------- layernorm
__global__ __launch_bounds__(256) void ln_kernel(
    const u16* __restrict__ Y, const float* __restrict__ g,
    const float* __restrict__ b, float* __restrict__ out)
{
    const int tid  = threadIdx.x;
    const u16* y = Y + (size_t)blockIdx.x * D_HID;
    float v[9];
    float s = 0.f, s2 = 0.f;
#pragma unroll
    for (int r = 0; r < 9; ++r) {
        v[r] = bf2f(y[tid + r * 256]);
        s += v[r]; s2 += v[r] * v[r];
    }
#pragma unroll
    for (int off = 32; off >= 1; off >>= 1) {
        s  += __shfl_xor(s, off);
        s2 += __shfl_xor(s2, off);
    }
    __shared__ float red[8];
    const int wave = tid >> 6;
    if ((tid & 63) == 0) { red[wave] = s; red[4 + wave] = s2; }
    __syncthreads();
    s  = red[0] + red[1] + red[2] + red[3];
    s2 = red[4] + red[5] + red[6] + red[7];
    const float inv_n = 1.0f / 2304.0f;
    float mu  = s * inv_n;
    float var = fmaxf(s2 * inv_n - mu * mu, 0.f);
    float inv = rsqrtf(var + 1e-5f);
    float* orow = out + (size_t)blockIdx.x * D_HID;
#pragma unroll
    for (int r = 0; r < 9; ++r) {
        int c = tid + r * 256;
        orow[c] = (v[r] - mu) * inv * g[c] + b[c];
    }
}

// ---------------------------------------------------------------- launch
extern "C" void kernel_launch(void* const* d_in, const int* in_sizes, int n_in,
                              void* d_out, int out_size, void* d_ws, size_t ws_size,
                              hipStream_t stream)
{
    const float* x   = (const float*)d_in[0];
    const float* wq  = (const float*)d_in[1];
    const float* bq  = (const float*)d_in[2];
    const float* wk  = (const float*)d_in[3];
    const float* bk  = (const float*)d_in[4];
    const float* wv  = (const float*)d_in[5];
    const float* bv  = (const float*)d_in[6];
    const float* wo  = (const float*)d_in[7];
    const float* bo  = (const float*)d_in[8];
    const float* lng = (const float*)d_in[9];
    const float* lnb = (const float*)d_in[10];

    char* ws = (char*)d_ws;
    size_t off = 0;
    auto alloc = [&](size_t bytes) {
        void* p = ws + off;
        off += (bytes + 255) & ~(size_t)255;
        return p;
    };
    u16*   xb   = (u16*)alloc((size_t)NTOK * D_HID * 2);
    u16*   wqkv = (u16*)alloc((size_t)(NQKV + D_HID) * D_HID * 2);
    u16*   wob  = wqkv + (size_t)NQKV * D_HID;
    float* bqkv = (float*)alloc((size_t)NQKV * 4);
    u16*   qkv  = (u16*)alloc((size_t)NTOK * NQKV * 2);
    u16*   aout = (u16*)alloc((size_t)NTOK * D_HID * 2);
    u16*   ybuf = qkv;  // QKV dead after attention; reuse for bf16 y

    cvt_f32_bf16<<<NTOK * D_HID / 1024, 256, 0, stream>>>(x, xb);
    cvt_weights<<<4 * WELEMS / 1024, 256, 0, stream>>>(wq, wk, wv, wo, wqkv,
                                                       bq, bk, bv, bqkv);
    gemm256_bt<<<(NTOK / 256) * (NQKV / 256), 512, 0, stream>>>(
        xb, wqkv, bqkv, qkv, NTOK, NQKV, D_HID);
    attn_headmix<<<NTOK, 256, 0, stream>>>(qkv, aout);
    gemm_bt<1><<<(D_HID / 128) * (NTOK / 128), 256, 0, stream>>>(
        aout, wob, bo, ybuf, xb, NTOK, D_HID, D_HID);
    ln_kernel<<<NTOK, 256, 0, stream>>>(ybuf, lng, lnb, (float*)d_out);
}

// Round 4
// 653.450 us; speedup vs baseline: 1.0600x; 1.0022x over previous
//
#include <hip/hip_runtime.h>
#include <stdint.h>
#include <stddef.h>

#define D_HID 2304
#define NTOK  8192          // 4 * 2048
#define NQKV  6912          // 3 * 2304
#define WELEMS 5308416      // 2304*2304
#define SEQ_MASK 2047

typedef unsigned short u16;
typedef __bf16 bf16x8 __attribute__((ext_vector_type(8)));
typedef float  f32x16 __attribute__((ext_vector_type(16)));
typedef float  f32x4  __attribute__((ext_vector_type(4)));

__device__ __forceinline__ u16 f2bf(float f) {
    unsigned int u = __builtin_bit_cast(unsigned int, f);
    u += 0x7fffu + ((u >> 16) & 1u);           // RNE
    return (u16)(u >> 16);
}
__device__ __forceinline__ float bf2f(u16 h) {
    unsigned int u = ((unsigned int)h) << 16;
    return __builtin_bit_cast(float, u);
}

__device__ __forceinline__ void gl2lds16(const void* g, void* l) {
    __builtin_amdgcn_global_load_lds(
        (const __attribute__((address_space(1))) void*)g,
        (__attribute__((address_space(3))) void*)l,
        16, 0, 0);
}

// ---------------------------------------------------------------- converts
__global__ __launch_bounds__(256) void cvt_f32_bf16(
    const float* __restrict__ src, u16* __restrict__ dst)
{
    size_t i = ((size_t)blockIdx.x * 256 + threadIdx.x) * 4;
    float4 f = *(const float4*)(src + i);
    ushort4 o = make_ushort4(f2bf(f.x), f2bf(f.y), f2bf(f.z), f2bf(f.w));
    *(ushort4*)(dst + i) = o;
}

__global__ __launch_bounds__(256) void cvt_weights(
    const float* __restrict__ wq, const float* __restrict__ wk,
    const float* __restrict__ wv, const float* __restrict__ wo,
    u16* __restrict__ dst,
    const float* __restrict__ bq, const float* __restrict__ bk,
    const float* __restrict__ bv, float* __restrict__ bqkv)
{
    int i = blockIdx.x * 256 + threadIdx.x;
    if (i < NQKV)
        bqkv[i] = (i < 2304) ? bq[i] : (i < 4608) ? bk[i - 2304] : bv[i - 4608];
    size_t base = (size_t)i * 4;
    int r = (int)(base / WELEMS);
    const float* src = (r == 0) ? wq : (r == 1) ? wk : (r == 2) ? wv : wo;
    float4 f = *(const float4*)(src + (base - (size_t)r * WELEMS));
    ushort4 o = make_ushort4(f2bf(f.x), f2bf(f.y), f2bf(f.z), f2bf(f.w));
    *(ushort4*)(dst + base) = o;
}

// ---------------------------------------------------------------- RoPE LUT
// lut[pos][2p] = cos, lut[pos][2p+1] = sin for pair p (0..1151), pos 0..2047.
// Same op sequence as the old inline path -> bit-identical values.
__global__ __launch_bounds__(256) void rope_lut_k(float* __restrict__ lut)
{
    const float OMEGA_C = -2.0f * 13.287712379549449f / 2304.0f;
    const float INV2PI  = 0.15915494309189535f;
    const float fpos = (float)blockIdx.x;
    float* row = lut + (size_t)blockIdx.x * 2304;
    for (int p = threadIdx.x; p < 1152; p += 256) {
        float omega = exp2f((float)p * OMEGA_C);
        float rr = fpos * omega * INV2PI;
        rr -= floorf(rr);
        float sn = __builtin_amdgcn_sinf(rr);
        float cs = __builtin_amdgcn_cosf(rr);
        *(float2*)(row + 2 * p) = make_float2(cs, sn);
    }
}

// ---------------------------------------------------------------- GEMM 256^2, read-pipelined 4-phase
// C[M,N] = A[M,K] * B[N,K]^T + bias, bf16 out. 512 thr = 8 waves (2M x 4N),
// per-wave 128x64 out via 16x16x32 MFMA. LDS = 2 K-tile buffers = 128 KiB.
//
// Phases split by k-half; fragment ds_reads issued ONE PHASE AHEAD of their
// MFMA. 4 barriers per K-tile (mid-barrier removed: c^1 pre-reads moved to
// ph4, after ph3's end-barrier which globalizes every wave's vmcnt(4)).
//   ph1: rd {Bk1(t), Aq1}   stage A1(t+1)->c^1        MFMA m0-3 kk0
//   ph2: rd {Aq2}           stage B0(t+2)->c          MFMA m4-7 kk0  lgkm0
//   ph3: rd {Aq3}           stage B1(t+2)->c  vmcnt(4) MFMA m0-3 kk1 lgkm0
//   ph4: rd {Bk0,Aq0(t+1)<-c^1}  stage A0(t+2)->c     MFMA m4-7 kk1  lgkm0
// Slot-overwrite ledger (overwrite always after a lgkm0+barrier draining the
// slot's last reads): B0(t) last read ph4(t-1) [drained ph4 lgkm0] < ph2(t)
// stage; B1(t) last read ph1(t) [drained ph2 lgkm0] < ph3(t) stage; A(t)
// last read ph3(t) [drained ph3 lgkm0] < ph4(t) stage; A1(t) in c last read
// ph3(t) < ph1(t+1) stage (barrier between). vmcnt(4) at ph3 retires
// A1(t+1) (in-order => ALL of tile t+1 landed); ph3's end-barrier makes
// that cross-wave before ph4's c^1 reads. Counted vmcnt never drains to 0
// in steady state (B0/B1(t+2) stay in flight).
// LDS 16B-chunk slot c' of row r holds global chunk c = c' ^ (r&7)
// (pre-swizzled global source, linear LDS dest, swizzled read).
__global__ __launch_bounds__(512, 2) void gemm256_bt(
    const u16* __restrict__ A, const u16* __restrict__ B,
    const float* __restrict__ bias, u16* __restrict__ Cout,
    int M, int N, int K)
{
    __shared__ __align__(16) u16 lds2[65536];   // 128 KiB

    const int tid  = threadIdx.x;
    const int lane = tid & 63;
    const int wave = tid >> 6;
    const int NT   = K >> 6;                    // 64-k tiles (36 for K=2304)
    (void)M;

    // XCD-bijective swizzle (grid % 8 == 0), bn-fast within each XCD chunk.
    const int chunk = gridDim.x >> 3;
    const int bid = (blockIdx.x & 7) * chunk + (blockIdx.x >> 3);
    const int num_bn = N >> 8;
    const int bm = bid / num_bn;
    const int bn = bid - bm * num_bn;

    // staging geometry: instr (wave, half) writes rows wave*8..+8 of a
    // 64-row stripe; lane l -> row +(l>>3), LDS slot l&7, source chunk
    // pre-swizzled = (l&7) ^ (l>>3).
    const int srow = lane >> 3;
    const u16* __restrict__ Ast = A + (size_t)(bm * 256 + wave * 8 + srow) * K
                                    + ((lane & 7) ^ srow) * 8;
    const u16* __restrict__ Bst = B + (size_t)(bn * 256 + wave * 8 + srow) * K
                                    + ((lane & 7) ^ srow) * 8;
    const size_t row64  = (size_t)64 * K;
    const size_t row128 = (size_t)128 * K;
    const int ldsW = wave * 512;

    // hsel: 0=A0 1=A1 2=B0 3=B1 of tile tt into buffer buf
#define STAGE(buf, hsel, tt) do {                                              \
    const u16* g_ = ((hsel) < 2 ? Ast : Bst)                                   \
                    + (((hsel) & 1) ? row128 : 0) + (size_t)(tt) * 64;         \
    u16* l_ = lds2 + (buf) * 32768 + (((hsel) < 2) ? 0 : 16384)                \
              + (((hsel) & 1) ? 8192 : 0) + ldsW;                              \
    gl2lds16(g_, l_);                                                          \
    gl2lds16(g_ + row64, l_ + 4096);                                           \
} while (0)

    // read geometry (16x16x32 fragments): row = mo*16 + (l&15),
    // k-chunk slot = (kk*4 + l>>4) ^ (lane&7).
    const int l15 = lane & 15, l4 = lane >> 4;
    const int aBase = (wave >> 2) * 8192 + l15 * 64;
    const int bBase = 16384 + ((wave >> 1) & 1) * 8192
                      + ((wave & 1) * 64 + l15) * 64;
    const int s0 = ((l4    ) ^ (lane & 7)) * 8;
    const int s1 = ((l4 + 4) ^ (lane & 7)) * 8;

    f32x4 acc[8][4] = {};
    bf16x8 Bk0[4], Bk1[4], Aev[4], Aod[4];

    // prologue: tile0 {B0,B1,A0,A1} + tile1 {B0,B1,A0}; vmcnt(6) retires
    // exactly tile0's 8 loads; preload tile0's kk0 fragments.
    STAGE(0, 2, 0); STAGE(0, 3, 0); STAGE(0, 0, 0); STAGE(0, 1, 0);
    STAGE(1, 2, 1); STAGE(1, 3, 1); STAGE(1, 0, 1);
    asm volatile("s_waitcnt vmcnt(6)" ::: "memory");
    __builtin_amdgcn_s_barrier();
#pragma unroll
    for (int n = 0; n < 4; ++n)
        Bk0[n] = *(const bf16x8*)(lds2 + bBase + n * 1024 + s0);
#pragma unroll
    for (int mo = 0; mo < 4; ++mo)
        Aev[mo] = *(const bf16x8*)(lds2 + aBase + mo * 1024 + s0);

    for (int t = 0; t < NT; ++t) {
        const int cur = t & 1;
        const u16* lc = lds2 + cur * 32768;
        const u16* ln = lds2 + (cur ^ 1) * 32768;
        const bool st1 = (t + 1 < NT);
        const bool st2 = (t + 2 < NT);

        // ---- phase 1: rd Bk1(t)+Aq1; stage A1(t+1); MFMA m0-3 kk0
#pragma unroll
        for (int n = 0; n < 4; ++n)
            Bk1[n] = *(const bf16x8*)(lc + bBase + n * 1024 + s1);
#pragma unroll
        for (int mo = 0; mo < 4; ++mo)
            Aod[mo] = *(const bf16x8*)(lc + aBase + (4 + mo) * 1024 + s0);
        if (st1) STAGE(cur ^ 1, 1, t + 1);
        __builtin_amdgcn_sched_barrier(0);
        __builtin_amdgcn_s_setprio(1);
#pragma unroll
        for (int mo = 0; mo < 4; ++mo)
#pragma unroll
            for (int n = 0; n < 4; ++n)
                acc[mo][n] = __builtin_amdgcn_mfma_f32_16x16x32_bf16(
                    Aev[mo], Bk0[n], acc[mo][n], 0, 0, 0);
        __builtin_amdgcn_s_setprio(0);
        __builtin_amdgcn_sched_barrier(0);
        __builtin_amdgcn_s_barrier();

        // ---- phase 2: rd Aq2; stage B0(t+2); MFMA m4-7 kk0; lgkm0
#pragma unroll
        for (int mo = 0; mo < 4; ++mo)
            Aev[mo] = *(const bf16x8*)(lc + aBase + mo * 1024 + s1);
        if (st2) STAGE(cur, 2, t + 2);
        __builtin_amdgcn_sched_barrier(0);
        __builtin_amdgcn_s_setprio(1);
#pragma unroll
        for (int mo = 0; mo < 4; ++mo)
#pragma unroll
            for (int n = 0; n < 4; ++n)
                acc[4 + mo][n] = __builtin_amdgcn_mfma_f32_16x16x32_bf16(
                    Aod[mo], Bk0[n], acc[4 + mo][n], 0, 0, 0);
        __builtin_amdgcn_s_setprio(0);
        __builtin_amdgcn_sched_barrier(0);
        asm volatile("s_waitcnt lgkmcnt(0)" ::: "memory");
        __builtin_amdgcn_s_barrier();

        // ---- phase 3: rd Aq3; stage B1(t+2); vmcnt(4); MFMA m0-3 kk1; lgkm0
#pragma unroll
        for (int mo = 0; mo < 4; ++mo)
            Aod[mo] = *(const bf16x8*)(lc + aBase + (4 + mo) * 1024 + s1);
        if (st2) STAGE(cur, 3, t + 2);
        if (st2)      asm volatile("s_waitcnt vmcnt(4)" ::: "memory");
        else if (st1) asm volatile("s_waitcnt vmcnt(0)" ::: "memory");
        __builtin_amdgcn_sched_barrier(0);
        __builtin_amdgcn_s_setprio(1);
#pragma unroll
        for (int mo = 0; mo < 4; ++mo)
#pragma unroll
            for (int n = 0; n < 4; ++n)
                acc[mo][n] = __builtin_amdgcn_mfma_f32_16x16x32_bf16(
                    Aev[mo], Bk1[n], acc[mo][n], 0, 0, 0);
        __builtin_amdgcn_s_setprio(0);
        __builtin_amdgcn_sched_barrier(0);
        asm volatile("s_waitcnt lgkmcnt(0)" ::: "memory");
        __builtin_amdgcn_s_barrier();

        // ---- phase 4: rd Bk0+Aq0(t+1) from c^1 (safe: all waves passed
        //      vmcnt(4) at ph3's barrier); stage A0(t+2); MFMA m4-7 kk1
        if (st1) {
#pragma unroll
            for (int n = 0; n < 4; ++n)
                Bk0[n] = *(const bf16x8*)(ln + bBase + n * 1024 + s0);
#pragma unroll
            for (int mo = 0; mo < 4; ++mo)
                Aev[mo] = *(const bf16x8*)(ln + aBase + mo * 1024 + s0);
        }
        if (st2) STAGE(cur, 0, t + 2);
        __builtin_amdgcn_sched_barrier(0);
        __builtin_amdgcn_s_setprio(1);
#pragma unroll
        for (int mo = 0; mo < 4; ++mo)
#pragma unroll
            for (int n = 0; n < 4; ++n)
                acc[4 + mo][n] = __builtin_amdgcn_mfma_f32_16x16x32_bf16(
                    Aod[mo], Bk1[n], acc[4 + mo][n], 0, 0, 0);
        __builtin_amdgcn_s_setprio(0);
        __builtin_amdgcn_sched_barrier(0);
        asm volatile("s_waitcnt lgkmcnt(0)" ::: "memory");
        __builtin_amdgcn_s_barrier();
    }
#undef STAGE

    // epilogue: C/D layout col = lane&15, row = (lane>>4)*4 + reg
    const int wm0 = (wave >> 2) * 128, wn0 = (wave & 3) * 64;
#pragma unroll
    for (int n = 0; n < 4; ++n) {
        const int gn = bn * 256 + wn0 + n * 16 + l15;
        const float bv = bias[gn];
#pragma unroll
        for (int m = 0; m < 8; ++m) {
            const int gm = bm * 256 + wm0 + m * 16 + l4 * 4;
#pragma unroll
            for (int j = 0; j < 4; ++j)
                Cout[(size_t)(gm + j) * N + gn] = f2bf(acc[m][n][j] + bv);
        }
    }
}

// ---------------------------------------------------------------- GEMM 128^2 (kept for O-proj)
// C[M,N] = A[M,K] * B[N,K]^T  (both K-major, bf16), fp32 accumulate.
// MODE 1: C = acc + bias + resid16 -> bf16 out (resid bf16)
template<int MODE>
__global__ __launch_bounds__(256, 3) void gemm_bt(
    const u16* __restrict__ A, const u16* __restrict__ B,
    const float* __restrict__ bias, u16* __restrict__ Cout,
    const u16* __restrict__ resid, int M, int N, int K)
{
    __shared__ __align__(16) u16 As[128 * 64];
    __shared__ __align__(16) u16 Bs[128 * 64];

    const int tid  = threadIdx.x;
    const int lane = tid & 63;
    const int wave = tid >> 6;

    // supertile decomposition: GROUP_M = 8 along bm, bm-fastest
    const int num_bn = N >> 7;
    const int rem = blockIdx.x % (num_bn << 3);
    const int bn  = rem >> 3;
    const int bm  = ((blockIdx.x / (num_bn << 3)) << 3) + (rem & 7);

    const int srow = tid >> 3;                        // 0..31
    const int sc   = (tid & 7) ^ (srow & 7);          // swizzle key = row&7
    const u16* Ag = A + (size_t)(bm * 128 + srow) * K + sc * 8;
    const u16* Bg = B + (size_t)(bn * 128 + srow) * K + sc * 8;
    const size_t row32 = (size_t)32 * K;
    u16* asd = As + wave * 512;                       // +r*2048 per round
    u16* bsd = Bs + wave * 512;

    const int rl = lane & 31;      // row within 32-tile (A: m, B: n)
    const int h  = lane >> 5;      // k-half of 16-k step
    const int swz = rl & 7;        // read-side swizzle key
    const int wm = (wave >> 1) * 64;
    const int wn = (wave & 1) * 64;

    f32x16 acc[2][2] = {};

    for (int kb = 0; kb < K; kb += 64) {
        __syncthreads();
#pragma unroll
        for (int r = 0; r < 4; ++r) {
            gl2lds16(Ag + kb + r * row32, asd + r * 2048);
            gl2lds16(Bg + kb + r * row32, bsd + r * 2048);
        }
        __syncthreads();

#pragma unroll
        for (int s = 0; s < 4; ++s) {                 // four 16-k steps
            const int ch = ((s * 2 + h) ^ swz) * 8;   // u16 offset of chunk
            bf16x8 a0 = *(const bf16x8*)(As + (wm      + rl) * 64 + ch);
            bf16x8 a1 = *(const bf16x8*)(As + (wm + 32 + rl) * 64 + ch);
            bf16x8 b0 = *(const bf16x8*)(Bs + (wn      + rl) * 64 + ch);
            bf16x8 b1 = *(const bf16x8*)(Bs + (wn + 32 + rl) * 64 + ch);
            acc[0][0] = __builtin_amdgcn_mfma_f32_32x32x16_bf16(a0, b0, acc[0][0], 0, 0, 0);
            acc[0][1] = __builtin_amdgcn_mfma_f32_32x32x16_bf16(a0, b1, acc[0][1], 0, 0, 0);
            acc[1][0] = __builtin_amdgcn_mfma_f32_32x32x16_bf16(a1, b0, acc[1][0], 0, 0, 0);
            acc[1][1] = __builtin_amdgcn_mfma_f32_32x32x16_bf16(a1, b1, acc[1][1], 0, 0, 0);
        }
    }

    // epilogue: C/D layout col = lane&31, row = (reg&3) + 8*(reg>>2) + 4*h
#pragma unroll
    for (int mt = 0; mt < 2; ++mt) {
#pragma unroll
        for (int nt = 0; nt < 2; ++nt) {
            const int gn = bn * 128 + wn + nt * 32 + rl;
            const float bv = bias[gn];
#pragma unroll
            for (int reg = 0; reg < 16; ++reg) {
                const int gm = bm * 128 + wm + mt * 32 +
                               (reg & 3) + 8 * (reg >> 2) + 4 * h;
                const size_t idx = (size_t)gm * N + gn;
                float v = acc[mt][nt][reg] + bv;
                if constexpr (MODE == 1) v += bf2f(resid[idx]);
                Cout[idx] = f2bf(v);
            }
        }
    }
}

// ---------------------------------------------------------------- attention
// One block per token. q/k/v staged as [16 heads][148 floats] (pad 144->148:
// row-to-row bank offset = 20 -> strided head reads conflict-free).
// RoPE cos/sin from precomputed LUT (q and k chunks read identical lines ->
// L1/L2 broadcast). S = QK^T/12 over d=144 per head pair, softmax over m
// (stored transposed), O-step: 144 tasks of (4 cols x 4 heads).
#define HROW 148
__global__ __launch_bounds__(256) void attn_headmix(
    const u16* __restrict__ QKV, const float* __restrict__ lut,
    u16* __restrict__ Aout)
{
    __shared__ __align__(16) float qs[16 * HROW];
    __shared__ __align__(16) float ks[16 * HROW];
    __shared__ __align__(16) float vs[16 * HROW];
    __shared__ __align__(16) float wsmT[256];   // wsmT[m][n]

    const int tid = threadIdx.x;
    const int t   = blockIdx.x;
    const u16* row = QKV + (size_t)t * NQKV;
    const float* lutrow = lut + (size_t)(t & SEQ_MASK) * 2304;

    for (int c = tid; c < 864; c += 256) {       // 864 chunks of 8 bf16
        uint4 raw = *(const uint4*)(row + c * 8);
        float f[8];
        f[0] = bf2f(raw.x & 0xffff); f[1] = bf2f(raw.x >> 16);
        f[2] = bf2f(raw.y & 0xffff); f[3] = bf2f(raw.y >> 16);
        f[4] = bf2f(raw.z & 0xffff); f[5] = bf2f(raw.z >> 16);
        f[6] = bf2f(raw.w & 0xffff); f[7] = bf2f(raw.w >> 16);
        if (c < 576) {                            // q or k chunk -> RoPE
            const int cc = (c < 288) ? c : c - 288;
            const float4 t0 = *(const float4*)(lutrow + cc * 8);
            const float4 t1 = *(const float4*)(lutrow + cc * 8 + 4);
            float x0, x1;
            x0 = f[0]; x1 = f[1]; f[0] = t0.x * x0 - t0.y * x1; f[1] = t0.y * x0 + t0.x * x1;
            x0 = f[2]; x1 = f[3]; f[2] = t0.z * x0 - t0.w * x1; f[3] = t0.w * x0 + t0.z * x1;
            x0 = f[4]; x1 = f[5]; f[4] = t1.x * x0 - t1.y * x1; f[5] = t1.y * x0 + t1.x * x1;
            x0 = f[6]; x1 = f[7]; f[6] = t1.z * x0 - t1.w * x1; f[7] = t1.w * x0 + t1.z * x1;
            const int hr = cc / 18, col = (cc - hr * 18) * 8;  // 18 chunks/head
            float* dst = ((c < 288) ? qs : ks) + hr * HROW + col;
            *(float4*)(dst)     = make_float4(f[0], f[1], f[2], f[3]);
            *(float4*)(dst + 4) = make_float4(f[4], f[5], f[6], f[7]);
        } else {
            const int cv = c - 576;
            const int hr = cv / 18, col = (cv - hr * 18) * 8;
            float* dst = vs + hr * HROW + col;
            *(float4*)(dst)     = make_float4(f[0], f[1], f[2], f[3]);
            *(float4*)(dst + 4) = make_float4(f[4], f[5], f[6], f[7]);
        }
    }
    __syncthreads();

    // S[n][m]: thread (n = tid>>4, m = tid&15)
    const int n = tid >> 4, m = tid & 15;
    const float* qr = qs + n * HROW;
    const float* kr = ks + m * HROW;
    float s = 0.f;
#pragma unroll
    for (int d = 0; d < 144; d += 4) {
        float4 qv = *(const float4*)(qr + d);
        float4 kv = *(const float4*)(kr + d);
        s += qv.x * kv.x + qv.y * kv.y + qv.z * kv.z + qv.w * kv.w;
    }
    s *= (1.0f / 12.0f);                         // 1/sqrt(144)

    float mx = s;
#pragma unroll
    for (int off = 8; off >= 1; off >>= 1) mx = fmaxf(mx, __shfl_xor(mx, off));
    float e = __expf(s - mx);
    float sum = e;
#pragma unroll
    for (int off = 8; off >= 1; off >>= 1) sum += __shfl_xor(sum, off);
    wsmT[m * 16 + n] = e / sum;                  // transposed store
    __syncthreads();

    // O: task = (col4 = 0..35, nq = 0..3); 144 active threads
    if (tid < 144) {
        const int col4 = tid % 36;
        const int nq   = tid / 36;
        const int oc   = col4 * 4;
        float4 a0 = {0,0,0,0}, a1 = {0,0,0,0}, a2 = {0,0,0,0}, a3 = {0,0,0,0};
#pragma unroll
        for (int mm = 0; mm < 16; ++mm) {
            float4 w4 = *(const float4*)(wsmT + mm * 16 + nq * 4);
            float4 v4 = *(const float4*)(vs + mm * HROW + oc);
            a0.x += w4.x * v4.x; a0.y += w4.x * v4.y; a0.z += w4.x * v4.z; a0.w += w4.x * v4.w;
            a1.x += w4.y * v4.x; a1.y += w4.y * v4.y; a1.z += w4.y * v4.z; a1.w += w4.y * v4.w;
            a2.x += w4.z * v4.x; a2.y += w4.z * v4.y; a2.z += w4.z * v4.z; a2.w += w4.z * v4.w;
            a3.x += w4.w * v4.x; a3.y += w4.w * v4.y; a3.z += w4.w * v4.z; a3.w += w4.w * v4.w;
        }
        u16* orow = Aout + (size_t)t * D_HID;
        float4 accs[4] = {a0, a1, a2, a3};
#pragma unroll
        for (int i = 0; i < 4; ++i) {
            const int nn = nq * 4 + i;
            ushort4 o = make_ushort4(f2bf(accs[i].x), f2bf(accs[i].y),
                                     f2bf(accs[i].z), f2bf(accs[i].w));
            *(ushort4*)(orow + nn * 144 + oc) = o;
        }
    }
}

// ---------------------------------------------------------------- layernorm
// Vectorized: thread t owns cols t*8..t*8+7 (uint4 = 8 bf16) + col 2048+t.
__global__ __launch_bounds__(256) void ln_kernel(
    const u16* __restrict__ Y, const float* __restrict__ g,
    const float* __restrict__ b, float* __restrict__ out)
{
    const int tid  = threadIdx.x;
    const u16* y = Y + (size_t)blockIdx.x * D_HID;
    uint4 raw = *(const uint4*)(y + tid * 8);
    u16 extra = y[2048 + tid];
    float v[9];
    v[0] = bf2f(raw.x & 0xffff); v[1] = bf2f(raw.x >> 16);
    v[2] = bf2f(raw.y & 0xffff); v[3] = bf2f(raw.y >> 16);
    v[4] = bf2f(raw.z & 0xffff); v[5] = bf2f(raw.z >> 16);
    v[6] = bf2f(raw.w & 0xffff); v[7] = bf2f(raw.w >> 16);
    v[8] = bf2f(extra);
    float s = 0.f, s2 = 0.f;
#pragma unroll
    for (int r = 0; r < 9; ++r) { s += v[r]; s2 += v[r] * v[r]; }
#pragma unroll
    for (int off = 32; off >= 1; off >>= 1) {
        s  += __shfl_xor(s, off);
        s2 += __shfl_xor(s2, off);
    }
    __shared__ float red[8];
    const int wave = tid >> 6;
    if ((tid & 63) == 0) { red[wave] = s; red[4 + wave] = s2; }
    __syncthreads();
    s  = red[0] + red[1] + red[2] + red[3];
    s2 = red[4] + red[5] + red[6] + red[7];
    const float inv_n = 1.0f / 2304.0f;
    float mu  = s * inv_n;
    float var = fmaxf(s2 * inv_n - mu * mu, 0.f);
    float inv = rsqrtf(var + 1e-5f);
    float* orow = out + (size_t)blockIdx.x * D_HID;
    float4 g0 = *(const float4*)(g + tid * 8);
    float4 g1 = *(const float4*)(g + tid * 8 + 4);
    float4 b0 = *(const float4*)(b + tid * 8);
    float4 b1 = *(const float4*)(b + tid * 8 + 4);
    float4 o0, o1;
    o0.x = (v[0] - mu) * inv * g0.x + b0.x;
    o0.y = (v[1] - mu) * inv * g0.y + b0.y;
    o0.z = (v[2] - mu) * inv * g0.z + b0.z;
    o0.w = (v[3] - mu) * inv * g0.w + b0.w;
    o1.x = (v[4] - mu) * inv * g1.x + b1.x;
    o1.y = (v[5] - mu) * inv * g1.y + b1.y;
    o1.z = (v[6] - mu) * inv * g1.z + b1.z;
    o1.w = (v[7] - mu) * inv * g1.w + b1.w;
    *(float4*)(orow + tid * 8)     = o0;
    *(float4*)(orow + tid * 8 + 4) = o1;
    orow[2048 + tid] = (v[8] - mu) * inv * g[2048 + tid] + b[2048 + tid];
}

// ---------------------------------------------------------------- launch
extern "C" void kernel_launch(void* const* d_in, const int* in_sizes, int n_in,
                              void* d_out, int out_size, void* d_ws, size_t ws_size,
                              hipStream_t stream)
{
    const float* x   = (const float*)d_in[0];
    const float* wq  = (const float*)d_in[1];
    const float* bq  = (const float*)d_in[2];
    const float* wk  = (const float*)d_in[3];
    const float* bk  = (const float*)d_in[4];
    const float* wv  = (const float*)d_in[5];
    const float* bv  = (const float*)d_in[6];
    const float* wo  = (const float*)d_in[7];
    const float* bo  = (const float*)d_in[8];
    const float* lng = (const float*)d_in[9];
    const float* lnb = (const float*)d_in[10];

    char* ws = (char*)d_ws;
    size_t off = 0;
    auto alloc = [&](size_t bytes) {
        void* p = ws + off;
        off += (bytes + 255) & ~(size_t)255;
        return p;
    };
    u16*   xb   = (u16*)alloc((size_t)NTOK * D_HID * 2);
    u16*   wqkv = (u16*)alloc((size_t)(NQKV + D_HID) * D_HID * 2);
    u16*   wob  = wqkv + (size_t)NQKV * D_HID;
    float* bqkv = (float*)alloc((size_t)NQKV * 4);
    u16*   qkv  = (u16*)alloc((size_t)NTOK * NQKV * 2);
    u16*   aout = (u16*)alloc((size_t)NTOK * D_HID * 2);
    float* lutw = (float*)alloc((size_t)2048 * 2304 * 4);
    u16*   ybuf = qkv;  // QKV dead after attention; reuse for bf16 y

    rope_lut_k<<<2048, 256, 0, stream>>>(lutw);
    cvt_f32_bf16<<<NTOK * D_HID / 1024, 256, 0, stream>>>(x, xb);
    cvt_weights<<<4 * WELEMS / 1024, 256, 0, stream>>>(wq, wk, wv, wo, wqkv,
                                                       bq, bk, bv, bqkv);
    gemm256_bt<<<(NTOK / 256) * (NQKV / 256), 512, 0, stream>>>(
        xb, wqkv, bqkv, qkv, NTOK, NQKV, D_HID);
    attn_headmix<<<NTOK, 256, 0, stream>>>(qkv, lutw, aout);
    gemm_bt<1><<<(D_HID / 128) * (NTOK / 128), 256, 0, stream>>>(
        aout, wob, bo, ybuf, xb, NTOK, D_HID, D_HID);
    ln_kernel<<<NTOK, 256, 0, stream>>>(ybuf, lng, lnb, (float*)d_out);
}

// Round 5
// 653.412 us; speedup vs baseline: 1.0601x; 1.0001x over previous
//
#include <hip/hip_runtime.h>
#include <stdint.h>
#include <stddef.h>

#define D_HID 2304
#define NTOK  8192          // 4 * 2048
#define NQKV  6912          // 3 * 2304
#define WELEMS 5308416      // 2304*2304
#define SEQ_MASK 2047

typedef unsigned short u16;
typedef __bf16 bf16x8 __attribute__((ext_vector_type(8)));
typedef unsigned short ushort8 __attribute__((ext_vector_type(8)));
typedef float  f32x16 __attribute__((ext_vector_type(16)));
typedef float  f32x4  __attribute__((ext_vector_type(4)));

__device__ __forceinline__ u16 f2bf(float f) {
    unsigned int u = __builtin_bit_cast(unsigned int, f);
    u += 0x7fffu + ((u >> 16) & 1u);           // RNE
    return (u16)(u >> 16);
}
__device__ __forceinline__ float bf2f(u16 h) {
    unsigned int u = ((unsigned int)h) << 16;
    return __builtin_bit_cast(float, u);
}

__device__ __forceinline__ void gl2lds16(const void* g, void* l) {
    __builtin_amdgcn_global_load_lds(
        (const __attribute__((address_space(1))) void*)g,
        (__attribute__((address_space(3))) void*)l,
        16, 0, 0);
}

// ---------------------------------------------------------------- converts
__global__ __launch_bounds__(256) void cvt_f32_bf16(
    const float* __restrict__ src, u16* __restrict__ dst)
{
    size_t i = ((size_t)blockIdx.x * 256 + threadIdx.x) * 4;
    float4 f = *(const float4*)(src + i);
    ushort4 o = make_ushort4(f2bf(f.x), f2bf(f.y), f2bf(f.z), f2bf(f.w));
    *(ushort4*)(dst + i) = o;
}

__global__ __launch_bounds__(256) void cvt_weights(
    const float* __restrict__ wq, const float* __restrict__ wk,
    const float* __restrict__ wv, const float* __restrict__ wo,
    u16* __restrict__ dst,
    const float* __restrict__ bq, const float* __restrict__ bk,
    const float* __restrict__ bv, float* __restrict__ bqkv)
{
    int i = blockIdx.x * 256 + threadIdx.x;
    if (i < NQKV)
        bqkv[i] = (i < 2304) ? bq[i] : (i < 4608) ? bk[i - 2304] : bv[i - 4608];
    size_t base = (size_t)i * 4;
    int r = (int)(base / WELEMS);
    const float* src = (r == 0) ? wq : (r == 1) ? wk : (r == 2) ? wv : wo;
    float4 f = *(const float4*)(src + (base - (size_t)r * WELEMS));
    ushort4 o = make_ushort4(f2bf(f.x), f2bf(f.y), f2bf(f.z), f2bf(f.w));
    *(ushort4*)(dst + base) = o;
}

// ---------------------------------------------------------------- RoPE LUT
// lut[pos][2p] = cos, lut[pos][2p+1] = sin for pair p (0..1151), pos 0..2047.
__global__ __launch_bounds__(256) void rope_lut_k(float* __restrict__ lut)
{
    const float OMEGA_C = -2.0f * 13.287712379549449f / 2304.0f;
    const float INV2PI  = 0.15915494309189535f;
    const float fpos = (float)blockIdx.x;
    float* row = lut + (size_t)blockIdx.x * 2304;
    for (int p = threadIdx.x; p < 1152; p += 256) {
        float omega = exp2f((float)p * OMEGA_C);
        float rr = fpos * omega * INV2PI;
        rr -= floorf(rr);
        float sn = __builtin_amdgcn_sinf(rr);
        float cs = __builtin_amdgcn_cosf(rr);
        *(float2*)(row + 2 * p) = make_float2(cs, sn);
    }
}

// ---------------------------------------------------------------- GEMM 256^2, read-pipelined 4-phase
// (unchanged from round 4 — 288 us, MfmaUtil ~40)
__global__ __launch_bounds__(512, 2) void gemm256_bt(
    const u16* __restrict__ A, const u16* __restrict__ B,
    const float* __restrict__ bias, u16* __restrict__ Cout,
    int M, int N, int K)
{
    __shared__ __align__(16) u16 lds2[65536];   // 128 KiB

    const int tid  = threadIdx.x;
    const int lane = tid & 63;
    const int wave = tid >> 6;
    const int NT   = K >> 6;                    // 64-k tiles (36 for K=2304)
    (void)M;

    const int chunk = gridDim.x >> 3;
    const int bid = (blockIdx.x & 7) * chunk + (blockIdx.x >> 3);
    const int num_bn = N >> 8;
    const int bm = bid / num_bn;
    const int bn = bid - bm * num_bn;

    const int srow = lane >> 3;
    const u16* __restrict__ Ast = A + (size_t)(bm * 256 + wave * 8 + srow) * K
                                    + ((lane & 7) ^ srow) * 8;
    const u16* __restrict__ Bst = B + (size_t)(bn * 256 + wave * 8 + srow) * K
                                    + ((lane & 7) ^ srow) * 8;
    const size_t row64  = (size_t)64 * K;
    const size_t row128 = (size_t)128 * K;
    const int ldsW = wave * 512;

#define STAGE(buf, hsel, tt) do {                                              \
    const u16* g_ = ((hsel) < 2 ? Ast : Bst)                                   \
                    + (((hsel) & 1) ? row128 : 0) + (size_t)(tt) * 64;         \
    u16* l_ = lds2 + (buf) * 32768 + (((hsel) < 2) ? 0 : 16384)                \
              + (((hsel) & 1) ? 8192 : 0) + ldsW;                              \
    gl2lds16(g_, l_);                                                          \
    gl2lds16(g_ + row64, l_ + 4096);                                           \
} while (0)

    const int l15 = lane & 15, l4 = lane >> 4;
    const int aBase = (wave >> 2) * 8192 + l15 * 64;
    const int bBase = 16384 + ((wave >> 1) & 1) * 8192
                      + ((wave & 1) * 64 + l15) * 64;
    const int s0 = ((l4    ) ^ (lane & 7)) * 8;
    const int s1 = ((l4 + 4) ^ (lane & 7)) * 8;

    f32x4 acc[8][4] = {};
    bf16x8 Bk0[4], Bk1[4], Aev[4], Aod[4];

    STAGE(0, 2, 0); STAGE(0, 3, 0); STAGE(0, 0, 0); STAGE(0, 1, 0);
    STAGE(1, 2, 1); STAGE(1, 3, 1); STAGE(1, 0, 1);
    asm volatile("s_waitcnt vmcnt(6)" ::: "memory");
    __builtin_amdgcn_s_barrier();
#pragma unroll
    for (int n = 0; n < 4; ++n)
        Bk0[n] = *(const bf16x8*)(lds2 + bBase + n * 1024 + s0);
#pragma unroll
    for (int mo = 0; mo < 4; ++mo)
        Aev[mo] = *(const bf16x8*)(lds2 + aBase + mo * 1024 + s0);

    for (int t = 0; t < NT; ++t) {
        const int cur = t & 1;
        const u16* lc = lds2 + cur * 32768;
        const u16* ln = lds2 + (cur ^ 1) * 32768;
        const bool st1 = (t + 1 < NT);
        const bool st2 = (t + 2 < NT);

        // ---- phase 1: rd Bk1(t)+Aq1; stage A1(t+1); MFMA m0-3 kk0
#pragma unroll
        for (int n = 0; n < 4; ++n)
            Bk1[n] = *(const bf16x8*)(lc + bBase + n * 1024 + s1);
#pragma unroll
        for (int mo = 0; mo < 4; ++mo)
            Aod[mo] = *(const bf16x8*)(lc + aBase + (4 + mo) * 1024 + s0);
        if (st1) STAGE(cur ^ 1, 1, t + 1);
        __builtin_amdgcn_sched_barrier(0);
        __builtin_amdgcn_s_setprio(1);
#pragma unroll
        for (int mo = 0; mo < 4; ++mo)
#pragma unroll
            for (int n = 0; n < 4; ++n)
                acc[mo][n] = __builtin_amdgcn_mfma_f32_16x16x32_bf16(
                    Aev[mo], Bk0[n], acc[mo][n], 0, 0, 0);
        __builtin_amdgcn_s_setprio(0);
        __builtin_amdgcn_sched_barrier(0);
        __builtin_amdgcn_s_barrier();

        // ---- phase 2: rd Aq2; stage B0(t+2); MFMA m4-7 kk0; lgkm0
#pragma unroll
        for (int mo = 0; mo < 4; ++mo)
            Aev[mo] = *(const bf16x8*)(lc + aBase + mo * 1024 + s1);
        if (st2) STAGE(cur, 2, t + 2);
        __builtin_amdgcn_sched_barrier(0);
        __builtin_amdgcn_s_setprio(1);
#pragma unroll
        for (int mo = 0; mo < 4; ++mo)
#pragma unroll
            for (int n = 0; n < 4; ++n)
                acc[4 + mo][n] = __builtin_amdgcn_mfma_f32_16x16x32_bf16(
                    Aod[mo], Bk0[n], acc[4 + mo][n], 0, 0, 0);
        __builtin_amdgcn_s_setprio(0);
        __builtin_amdgcn_sched_barrier(0);
        asm volatile("s_waitcnt lgkmcnt(0)" ::: "memory");
        __builtin_amdgcn_s_barrier();

        // ---- phase 3: rd Aq3; stage B1(t+2); vmcnt(4); MFMA m0-3 kk1; lgkm0
#pragma unroll
        for (int mo = 0; mo < 4; ++mo)
            Aod[mo] = *(const bf16x8*)(lc + aBase + (4 + mo) * 1024 + s1);
        if (st2) STAGE(cur, 3, t + 2);
        if (st2)      asm volatile("s_waitcnt vmcnt(4)" ::: "memory");
        else if (st1) asm volatile("s_waitcnt vmcnt(0)" ::: "memory");
        __builtin_amdgcn_sched_barrier(0);
        __builtin_amdgcn_s_setprio(1);
#pragma unroll
        for (int mo = 0; mo < 4; ++mo)
#pragma unroll
            for (int n = 0; n < 4; ++n)
                acc[mo][n] = __builtin_amdgcn_mfma_f32_16x16x32_bf16(
                    Aev[mo], Bk1[n], acc[mo][n], 0, 0, 0);
        __builtin_amdgcn_s_setprio(0);
        __builtin_amdgcn_sched_barrier(0);
        asm volatile("s_waitcnt lgkmcnt(0)" ::: "memory");
        __builtin_amdgcn_s_barrier();

        // ---- phase 4: rd Bk0+Aq0(t+1) from c^1; stage A0(t+2); MFMA m4-7 kk1
        if (st1) {
#pragma unroll
            for (int n = 0; n < 4; ++n)
                Bk0[n] = *(const bf16x8*)(ln + bBase + n * 1024 + s0);
#pragma unroll
            for (int mo = 0; mo < 4; ++mo)
                Aev[mo] = *(const bf16x8*)(ln + aBase + mo * 1024 + s0);
        }
        if (st2) STAGE(cur, 0, t + 2);
        __builtin_amdgcn_sched_barrier(0);
        __builtin_amdgcn_s_setprio(1);
#pragma unroll
        for (int mo = 0; mo < 4; ++mo)
#pragma unroll
            for (int n = 0; n < 4; ++n)
                acc[4 + mo][n] = __builtin_amdgcn_mfma_f32_16x16x32_bf16(
                    Aod[mo], Bk1[n], acc[4 + mo][n], 0, 0, 0);
        __builtin_amdgcn_s_setprio(0);
        __builtin_amdgcn_sched_barrier(0);
        asm volatile("s_waitcnt lgkmcnt(0)" ::: "memory");
        __builtin_amdgcn_s_barrier();
    }
#undef STAGE

    // epilogue: C/D layout col = lane&15, row = (lane>>4)*4 + reg
    const int wm0 = (wave >> 2) * 128, wn0 = (wave & 3) * 64;
#pragma unroll
    for (int n = 0; n < 4; ++n) {
        const int gn = bn * 256 + wn0 + n * 16 + l15;
        const float bv = bias[gn];
#pragma unroll
        for (int m = 0; m < 8; ++m) {
            const int gm = bm * 256 + wm0 + m * 16 + l4 * 4;
#pragma unroll
            for (int j = 0; j < 4; ++j)
                Cout[(size_t)(gm + j) * N + gn] = f2bf(acc[m][n][j] + bv);
        }
    }
}

// ---------------------------------------------------------------- GEMM 128^2 (kept for O-proj)
template<int MODE>
__global__ __launch_bounds__(256, 3) void gemm_bt(
    const u16* __restrict__ A, const u16* __restrict__ B,
    const float* __restrict__ bias, u16* __restrict__ Cout,
    const u16* __restrict__ resid, int M, int N, int K)
{
    __shared__ __align__(16) u16 As[128 * 64];
    __shared__ __align__(16) u16 Bs[128 * 64];

    const int tid  = threadIdx.x;
    const int lane = tid & 63;
    const int wave = tid >> 6;

    const int num_bn = N >> 7;
    const int rem = blockIdx.x % (num_bn << 3);
    const int bn  = rem >> 3;
    const int bm  = ((blockIdx.x / (num_bn << 3)) << 3) + (rem & 7);

    const int srow = tid >> 3;                        // 0..31
    const int sc   = (tid & 7) ^ (srow & 7);          // swizzle key = row&7
    const u16* Ag = A + (size_t)(bm * 128 + srow) * K + sc * 8;
    const u16* Bg = B + (size_t)(bn * 128 + srow) * K + sc * 8;
    const size_t row32 = (size_t)32 * K;
    u16* asd = As + wave * 512;
    u16* bsd = Bs + wave * 512;

    const int rl = lane & 31;
    const int h  = lane >> 5;
    const int swz = rl & 7;
    const int wm = (wave >> 1) * 64;
    const int wn = (wave & 1) * 64;

    f32x16 acc[2][2] = {};

    for (int kb = 0; kb < K; kb += 64) {
        __syncthreads();
#pragma unroll
        for (int r = 0; r < 4; ++r) {
            gl2lds16(Ag + kb + r * row32, asd + r * 2048);
            gl2lds16(Bg + kb + r * row32, bsd + r * 2048);
        }
        __syncthreads();

#pragma unroll
        for (int s = 0; s < 4; ++s) {
            const int ch = ((s * 2 + h) ^ swz) * 8;
            bf16x8 a0 = *(const bf16x8*)(As + (wm      + rl) * 64 + ch);
            bf16x8 a1 = *(const bf16x8*)(As + (wm + 32 + rl) * 64 + ch);
            bf16x8 b0 = *(const bf16x8*)(Bs + (wn      + rl) * 64 + ch);
            bf16x8 b1 = *(const bf16x8*)(Bs + (wn + 32 + rl) * 64 + ch);
            acc[0][0] = __builtin_amdgcn_mfma_f32_32x32x16_bf16(a0, b0, acc[0][0], 0, 0, 0);
            acc[0][1] = __builtin_amdgcn_mfma_f32_32x32x16_bf16(a0, b1, acc[0][1], 0, 0, 0);
            acc[1][0] = __builtin_amdgcn_mfma_f32_32x32x16_bf16(a1, b0, acc[1][0], 0, 0, 0);
            acc[1][1] = __builtin_amdgcn_mfma_f32_32x32x16_bf16(a1, b1, acc[1][1], 0, 0, 0);
        }
    }

#pragma unroll
    for (int mt = 0; mt < 2; ++mt) {
#pragma unroll
        for (int nt = 0; nt < 2; ++nt) {
            const int gn = bn * 128 + wn + nt * 32 + rl;
            const float bv = bias[gn];
#pragma unroll
            for (int reg = 0; reg < 16; ++reg) {
                const int gm = bm * 128 + wm + mt * 32 +
                               (reg & 3) + 8 * (reg >> 2) + 4 * h;
                const size_t idx = (size_t)gm * N + gn;
                float v = acc[mt][nt][reg] + bv;
                if constexpr (MODE == 1) v += bf2f(resid[idx]);
                Cout[idx] = f2bf(v);
            }
        }
    }
}

// ---------------------------------------------------------------- attention (wave-per-token, MFMA)
// One WAVE per token; 8 waves / 512-thr block; NO block barriers (waves
// independent, per-wave LDS slices disjoint -> compiler's own lgkmcnt waits
// suffice).  Per token:
//   S = Q K^T / 12  : 16x16x144 K-major GEMM = 5x mfma_16x16x32 (d padded to
//     160; lanes l4>=2 of chunk 4 supply zeros). A/B frags load DIRECTLY from
//     global (rows are 144 bf16: frag = contiguous bf16x8 at h*144+kc*32+l4*8)
//     with RoPE applied in-register from the LUT (q,k share cos/sin loads).
//   softmax over m = shfl_xor across 16-lane groups (C layout: col m = l&15,
//     row n = (l>>4)*4+reg), per-reg independent.
//   O = W V : W->bf16 into WT[16][24] (48B rows: 16B-aligned, 2-way banks);
//     V transposed into VT[144][16] (32B rows) during load phase; 9x mfma
//     (K=16 effective, l4>=2 lanes zero); scalar u16 stores (4x32B segs/instr).
// LDS 8 x 5376B = 43 KiB -> 3 blocks/CU.
__device__ __forceinline__ ushort8 rope8(ushort8 v, float4 t0, float4 t1) {
    ushort8 o;
    float x0, x1;
    x0 = bf2f(v[0]); x1 = bf2f(v[1]);
    o[0] = f2bf(t0.x * x0 - t0.y * x1); o[1] = f2bf(t0.y * x0 + t0.x * x1);
    x0 = bf2f(v[2]); x1 = bf2f(v[3]);
    o[2] = f2bf(t0.z * x0 - t0.w * x1); o[3] = f2bf(t0.w * x0 + t0.z * x1);
    x0 = bf2f(v[4]); x1 = bf2f(v[5]);
    o[4] = f2bf(t1.x * x0 - t1.y * x1); o[5] = f2bf(t1.y * x0 + t1.x * x1);
    x0 = bf2f(v[6]); x1 = bf2f(v[7]);
    o[6] = f2bf(t1.z * x0 - t1.w * x1); o[7] = f2bf(t1.w * x0 + t1.z * x1);
    return o;
}

__global__ __launch_bounds__(512) void attn_mfma(
    const u16* __restrict__ QKV, const float* __restrict__ lut,
    u16* __restrict__ Aout)
{
    __shared__ __align__(16) u16 smem[8 * 2688];   // 43008 B
    const int tid  = threadIdx.x;
    const int lane = tid & 63;
    const int wave = tid >> 6;
    const int t    = blockIdx.x * 8 + wave;
    const int l15  = lane & 15, l4 = lane >> 4;

    u16* VT = smem + wave * 2688;          // [144][16] u16 (rows 32B)
    u16* WT = VT + 2304;                   // [16][24]  u16 (rows 48B)

    const u16* row = QKV + (size_t)t * NQKV;
    const float* lutrow = lut + (size_t)(t & SEQ_MASK) * 2304;

    // ---- q/k fragments (+RoPE) straight from global
    bf16x8 qf[5], kf[5];
#pragma unroll
    for (int kc = 0; kc < 5; ++kc) {
        const int dbase = kc * 32 + l4 * 8;
        ushort8 qv = {}, kv = {};
        if (dbase < 144) {
            qv = *(const ushort8*)(row + l15 * 144 + dbase);
            kv = *(const ushort8*)(row + 2304 + l15 * 144 + dbase);
            const float* lp = lutrow + l15 * 144 + dbase;   // = 2*pair_idx
            float4 c0 = *(const float4*)(lp);
            float4 c1 = *(const float4*)(lp + 4);
            qv = rope8(qv, c0, c1);
            kv = rope8(kv, c0, c1);
        }
        qf[kc] = __builtin_bit_cast(bf16x8, qv);
        kf[kc] = __builtin_bit_cast(bf16x8, kv);
    }

    // ---- V -> VT (transposed) for the O-step B-fragments
#pragma unroll
    for (int kc = 0; kc < 5; ++kc) {
        const int dbase = kc * 32 + l4 * 8;
        if (dbase < 144) {
            ushort8 vv = *(const ushort8*)(row + 4608 + l15 * 144 + dbase);
#pragma unroll
            for (int j = 0; j < 8; ++j)
                VT[(dbase + j) * 16 + l15] = vv[j];
        }
    }

    // ---- S = Q K^T (fp32 accum)
    f32x4 S = {};
#pragma unroll
    for (int kc = 0; kc < 5; ++kc)
        S = __builtin_amdgcn_mfma_f32_16x16x32_bf16(qf[kc], kf[kc], S, 0, 0, 0);

    // ---- softmax over m (across the 16-lane group), one row n per reg
#pragma unroll
    for (int r = 0; r < 4; ++r) {
        float s = S[r] * (1.0f / 12.0f);
        float mx = s;
#pragma unroll
        for (int off = 8; off >= 1; off >>= 1) mx = fmaxf(mx, __shfl_xor(mx, off));
        float e = __expf(s - mx);
        float sum = e;
#pragma unroll
        for (int off = 8; off >= 1; off >>= 1) sum += __shfl_xor(sum, off);
        WT[(l4 * 4 + r) * 24 + l15] = f2bf(e / sum);
    }

    // ---- O = W V : A-frag W[n=l15][m=l4*8+j] (l4<2, else zero)
    bf16x8 wA = {};
    if (l4 < 2) wA = *(const bf16x8*)(WT + l15 * 24 + l4 * 8);

    u16* orow = Aout + (size_t)t * D_HID;
#pragma unroll
    for (int db = 0; db < 9; ++db) {
        bf16x8 vB = {};
        if (l4 < 2) vB = *(const bf16x8*)(VT + (db * 16 + l15) * 16 + l4 * 8);
        f32x4 o = {};
        o = __builtin_amdgcn_mfma_f32_16x16x32_bf16(wA, vB, o, 0, 0, 0);
#pragma unroll
        for (int r = 0; r < 4; ++r)
            orow[(l4 * 4 + r) * 144 + db * 16 + l15] = f2bf(o[r]);
    }
}

// ---------------------------------------------------------------- layernorm
// Vectorized: thread t owns cols t*8..t*8+7 (uint4 = 8 bf16) + col 2048+t.
__global__ __launch_bounds__(256) void ln_kernel(
    const u16* __restrict__ Y, const float* __restrict__ g,
    const float* __restrict__ b, float* __restrict__ out)
{
    const int tid  = threadIdx.x;
    const u16* y = Y + (size_t)blockIdx.x * D_HID;
    uint4 raw = *(const uint4*)(y + tid * 8);
    u16 extra = y[2048 + tid];
    float v[9];
    v[0] = bf2f(raw.x & 0xffff); v[1] = bf2f(raw.x >> 16);
    v[2] = bf2f(raw.y & 0xffff); v[3] = bf2f(raw.y >> 16);
    v[4] = bf2f(raw.z & 0xffff); v[5] = bf2f(raw.z >> 16);
    v[6] = bf2f(raw.w & 0xffff); v[7] = bf2f(raw.w >> 16);
    v[8] = bf2f(extra);
    float s = 0.f, s2 = 0.f;
#pragma unroll
    for (int r = 0; r < 9; ++r) { s += v[r]; s2 += v[r] * v[r]; }
#pragma unroll
    for (int off = 32; off >= 1; off >>= 1) {
        s  += __shfl_xor(s, off);
        s2 += __shfl_xor(s2, off);
    }
    __shared__ float red[8];
    const int wave = tid >> 6;
    if ((tid & 63) == 0) { red[wave] = s; red[4 + wave] = s2; }
    __syncthreads();
    s  = red[0] + red[1] + red[2] + red[3];
    s2 = red[4] + red[5] + red[6] + red[7];
    const float inv_n = 1.0f / 2304.0f;
    float mu  = s * inv_n;
    float var = fmaxf(s2 * inv_n - mu * mu, 0.f);
    float inv = rsqrtf(var + 1e-5f);
    float* orow = out + (size_t)blockIdx.x * D_HID;
    float4 g0 = *(const float4*)(g + tid * 8);
    float4 g1 = *(const float4*)(g + tid * 8 + 4);
    float4 b0 = *(const float4*)(b + tid * 8);
    float4 b1 = *(const float4*)(b + tid * 8 + 4);
    float4 o0, o1;
    o0.x = (v[0] - mu) * inv * g0.x + b0.x;
    o0.y = (v[1] - mu) * inv * g0.y + b0.y;
    o0.z = (v[2] - mu) * inv * g0.z + b0.z;
    o0.w = (v[3] - mu) * inv * g0.w + b0.w;
    o1.x = (v[4] - mu) * inv * g1.x + b1.x;
    o1.y = (v[5] - mu) * inv * g1.y + b1.y;
    o1.z = (v[6] - mu) * inv * g1.z + b1.z;
    o1.w = (v[7] - mu) * inv * g1.w + b1.w;
    *(float4*)(orow + tid * 8)     = o0;
    *(float4*)(orow + tid * 8 + 4) = o1;
    orow[2048 + tid] = (v[8] - mu) * inv * g[2048 + tid] + b[2048 + tid];
}

// ---------------------------------------------------------------- launch
extern "C" void kernel_launch(void* const* d_in, const int* in_sizes, int n_in,
                              void* d_out, int out_size, void* d_ws, size_t ws_size,
                              hipStream_t stream)
{
    const float* x   = (const float*)d_in[0];
    const float* wq  = (const float*)d_in[1];
    const float* bq  = (const float*)d_in[2];
    const float* wk  = (const float*)d_in[3];
    const float* bk  = (const float*)d_in[4];
    const float* wv  = (const float*)d_in[5];
    const float* bv  = (const float*)d_in[6];
    const float* wo  = (const float*)d_in[7];
    const float* bo  = (const float*)d_in[8];
    const float* lng = (const float*)d_in[9];
    const float* lnb = (const float*)d_in[10];

    char* ws = (char*)d_ws;
    size_t off = 0;
    auto alloc = [&](size_t bytes) {
        void* p = ws + off;
        off += (bytes + 255) & ~(size_t)255;
        return p;
    };
    u16*   xb   = (u16*)alloc((size_t)NTOK * D_HID * 2);
    u16*   wqkv = (u16*)alloc((size_t)(NQKV + D_HID) * D_HID * 2);
    u16*   wob  = wqkv + (size_t)NQKV * D_HID;
    float* bqkv = (float*)alloc((size_t)NQKV * 4);
    u16*   qkv  = (u16*)alloc((size_t)NTOK * NQKV * 2);
    u16*   aout = (u16*)alloc((size_t)NTOK * D_HID * 2);
    float* lutw = (float*)alloc((size_t)2048 * 2304 * 4);
    u16*   ybuf = qkv;  // QKV dead after attention; reuse for bf16 y

    rope_lut_k<<<2048, 256, 0, stream>>>(lutw);
    cvt_f32_bf16<<<NTOK * D_HID / 1024, 256, 0, stream>>>(x, xb);
    cvt_weights<<<4 * WELEMS / 1024, 256, 0, stream>>>(wq, wk, wv, wo, wqkv,
                                                       bq, bk, bv, bqkv);
    gemm256_bt<<<(NTOK / 256) * (NQKV / 256), 512, 0, stream>>>(
        xb, wqkv, bqkv, qkv, NTOK, NQKV, D_HID);
    attn_mfma<<<NTOK / 8, 512, 0, stream>>>(qkv, lutw, aout);
    gemm_bt<1><<<(D_HID / 128) * (NTOK / 128), 256, 0, stream>>>(
        aout, wob, bo, ybuf, xb, NTOK, D_HID, D_HID);
    ln_kernel<<<NTOK, 256, 0, stream>>>(ybuf, lng, lnb, (float*)d_out);
}